// Round 9
// baseline (2818.398 us; speedup 1.0000x reference)
//
#include <hip/hip_runtime.h>
#include <hip/hip_bf16.h>
#include <cstdint>

#define B_ 32
#define T_ 1024
#define E_ 256
#define H_ 256
#define G_ 1024
#define NTAG 14

typedef __bf16 bf8_t __attribute__((ext_vector_type(8)));
typedef float f4_t __attribute__((ext_vector_type(4)));
typedef int i4_t __attribute__((ext_vector_type(4)));
typedef unsigned short u16x4 __attribute__((ext_vector_type(4)));

__device__ __forceinline__ unsigned short f2bf(float f) {
    unsigned u = __builtin_bit_cast(unsigned, f);
    u = u + 0x7FFFu + ((u >> 16) & 1u);
    return (unsigned short)(u >> 16);
}
__device__ __forceinline__ float bf2f(unsigned short s) {
    unsigned u = ((unsigned)s) << 16;
    return __builtin_bit_cast(float, u);
}
__device__ __forceinline__ float sigf(float x) { return 1.0f / (1.0f + __expf(-x)); }
// branch-free tanh: overflow-safe (exp->inf => 1; exp->0 => -1)
__device__ __forceinline__ float tanh2_(float x) {
    float e = __expf(2.0f * x);
    return 1.0f - 2.0f / (e + 1.0f);
}
__device__ __forceinline__ f4_t mfma16(bf8_t a, bf8_t b, f4_t c) {
    return __builtin_amdgcn_mfma_f32_16x16x32_bf16(a, b, c, 0, 0, 0);
}

// ---------------- prep: wih->bf16, combine biases, wout pad ----------------
__global__ __launch_bounds__(256) void prep_kernel(
        const float* wih_f, const float* wih_b,
        const float* bih_f, const float* bhh_f,
        const float* bih_b, const float* bhh_b,
        const float* wout,
        unsigned short* wih_bf, float* biasc, unsigned short* wout_bf) {
    int tid = blockIdx.x * 256 + threadIdx.x;
    if (tid < 524288) {                       // 2 x 262144: [d][1024][256]
        int d = tid >> 18, off = tid & 262143;
        wih_bf[tid] = f2bf((d ? wih_b : wih_f)[off]);
        return;
    }
    int t2 = tid - 524288;
    if (t2 < 8192) {                          // wout padded [16][512]
        int n = t2 >> 9, k = t2 & 511;
        wout_bf[t2] = (n < NTAG) ? f2bf(wout[n * 512 + k]) : (unsigned short)0;
        return;
    }
    int t3 = t2 - 8192;
    if (t3 < 2048) {                          // biasc [2][1024]
        int d = t3 >> 10, g = t3 & 1023;
        biasc[t3] = d ? (bih_b[g] + bhh_b[g]) : (bih_f[g] + bhh_f[g]);
    }
}

// ---------------- whh -> int8 with per-row scale ----------------
__global__ __launch_bounds__(256) void wquant_kernel(const float* whh_f, const float* whh_b,
                                                     signed char* qw, float* sw) {
    int row = blockIdx.x * 4 + (threadIdx.x >> 6);   // 0..2047 = [d][1024]
    int l = threadIdx.x & 63;
    int d = row >> 10, rr = row & 1023;
    const float* src = (d ? whh_b : whh_f) + (size_t)rr * 256;
    float4 v = *reinterpret_cast<const float4*>(src + 4 * l);
    float am = fmaxf(fmaxf(fabsf(v.x), fabsf(v.y)), fmaxf(fabsf(v.z), fabsf(v.w)));
#pragma unroll
    for (int off = 1; off < 64; off <<= 1)
        am = fmaxf(am, __shfl_xor(am, off));
    am = fmaxf(am, 1e-20f);
    float inv = 127.f / am;
    int q0 = (int)__builtin_rintf(v.x * inv), q1 = (int)__builtin_rintf(v.y * inv);
    int q2 = (int)__builtin_rintf(v.z * inv), q3 = (int)__builtin_rintf(v.w * inv);
    unsigned u = (q0 & 255) | ((q1 & 255) << 8) | ((q2 & 255) << 16) | ((q3 & 255) << 24);
    *reinterpret_cast<unsigned*>(qw + (size_t)row * 256 + 4 * l) = u;
    if (l == 0) sw[row] = am / 127.f;
}

// ---------------- embedding gather -> bf16 ----------------
__global__ __launch_bounds__(256) void embed_kernel(const int* sent, const float* emb,
                                                    unsigned short* xbf) {
    int tid = blockIdx.x * 256 + threadIdx.x; // 32768*64 threads
    int bt = tid >> 6;
    int e0 = (tid & 63) << 2;
    int tok = sent[bt];
    float4 v = *reinterpret_cast<const float4*>(emb + (size_t)tok * E_ + e0);
    u16x4 o;
    o[0] = f2bf(v.x); o[1] = f2bf(v.y); o[2] = f2bf(v.z); o[3] = f2bf(v.w);
    *reinterpret_cast<u16x4*>(xbf + (size_t)bt * E_ + e0) = o;
}

// ---- input projection -> xg4[d*16+b2][t][m 2][1024 n]; B pinned in regs, 16-t loop ----
__global__ __launch_bounds__(256, 1) void xproj_kernel(const unsigned short* xbf,
        const unsigned short* wih_bf, const float* biasc, unsigned short* xg4) {
    int tt = blockIdx.x;                 // 0..63 (16 t each)
    int y = blockIdx.y;                  // d*8 + bh*4 + ns
    int ns = y & 3, bh = (y >> 2) & 1, d = y >> 3;
    int w = threadIdx.x >> 6, l = threadIdx.x & 63;
    int l15 = l & 15, lgp = l >> 4;
    __shared__ unsigned short sh[256][16];

    // B fragments: this wave's 64 n-cols x 256 k, resident for the whole t-loop
    int nbase = ns * 256 + w * 64;
    const unsigned short* wd = wih_bf + (size_t)d * 262144;
    bf8_t breg[4][8];
    float bias[4];
#pragma unroll
    for (int p = 0; p < 4; ++p) {
        int n = nbase + 16 * p + l15;
        bias[p] = biasc[d * G_ + n];
        const unsigned short* brow = wd + (size_t)n * E_ + 8 * lgp;
#pragma unroll
        for (int ks = 0; ks < 8; ++ks)
            breg[p][ks] = *reinterpret_cast<const bf8_t*>(brow + 32 * ks);
    }
#pragma unroll
    for (int p = 0; p < 4; ++p)
#pragma unroll
        for (int ks = 0; ks < 8; ++ks)
            asm volatile("" : "+v"(breg[p][ks]));

    const unsigned short* arow =
        xbf + ((size_t)(16 * bh + l15) * 1024 + tt * 16) * E_ + 8 * lgp;

    for (int it = 0; it < 16; ++it) {
        int t = tt * 16 + it;
        bf8_t a[8];
#pragma unroll
        for (int ks = 0; ks < 8; ++ks)
            a[ks] = *reinterpret_cast<const bf8_t*>(arow + 32 * ks);
        arow += 256;

        f4_t acc[4];
#pragma unroll
        for (int p = 0; p < 4; ++p) { acc[p][0] = 0.f; acc[p][1] = 0.f; acc[p][2] = 0.f; acc[p][3] = 0.f; }
#pragma unroll
        for (int p = 0; p < 4; ++p)
#pragma unroll
            for (int ks = 0; ks < 8; ++ks)
                acc[p] = mfma16(a[ks], breg[p][ks], acc[p]);

#pragma unroll
        for (int p = 0; p < 4; ++p)
#pragma unroll
            for (int r = 0; r < 4; ++r)
                sh[w * 64 + 16 * p + l15][4 * lgp + r] = f2bf(acc[p][r] + bias[p]);
        __syncthreads();
        // writeout: thread q owns n = ns*256+q; coalesced 2B stores
        int q = threadIdx.x;
#pragma unroll
        for (int p = 0; p < 8; ++p) {
            int b2g = 8 * bh + p;
            size_t base = ((size_t)(d * 16 + b2g) * 1024 + t) * 2048 + ns * 256 + q;
            xg4[base]        = sh[q][2 * p];      // m=0
            xg4[base + 1024] = sh[q][2 * p + 1];  // m=1
        }
        __syncthreads();   // protect sh reuse next iteration
    }
}

// ------- recurrence: 32 WGs = (dir, batch-pair); in-lane epilogue, 1 barrier/step ----
__global__ __launch_bounds__(512, 2) void lstm_kernel(const unsigned short* xg4,
        const signed char* qw, const float* sw, const float* h0, const float* c0,
        unsigned short* hs) {
    int bid = blockIdx.x;            // 0..31
    int b2 = bid & 15, d = bid >> 4;
    int tid = threadIdx.x;
    int w = tid >> 6, l = tid & 63, l15 = l & 15, lgp = l >> 4;

    __shared__ __attribute__((aligned(16))) signed char h8[2][2][320]; // parity x m x col
    __shared__ i4_t wsh[4096];       // 64 KiB: ks=3 weight quarter
    __shared__ float red_sh[8];

    const signed char* qwd = qw + (size_t)d * 262144;

    // ks 0..2 weights -> registers (24 quads = 96 regs)
    i4_t wreg[4][2][3];
#pragma unroll
    for (int gt = 0; gt < 4; ++gt)
#pragma unroll
        for (int jt = 0; jt < 2; ++jt) {
            int n = 256 * gt + 32 * w + 16 * jt + l15;
#pragma unroll
            for (int ks = 0; ks < 3; ++ks)
                wreg[gt][jt][ks] = *reinterpret_cast<const i4_t*>(
                    qwd + (size_t)n * 256 + 64 * ks + 16 * lgp);
        }
#pragma unroll
    for (int gt = 0; gt < 4; ++gt)
#pragma unroll
        for (int jt = 0; jt < 2; ++jt)
#pragma unroll
            for (int ks = 0; ks < 3; ++ks)
                asm volatile("" : "+v"(wreg[gt][jt][ks]));   // keep resident

    // ks=3 weights -> LDS
#pragma unroll
    for (int gt = 0; gt < 4; ++gt)
#pragma unroll
        for (int jt = 0; jt < 2; ++jt) {
            int n = 256 * gt + 32 * w + 16 * jt + l15;
            wsh[(w * 8 + gt * 2 + jt) * 64 + l] = *reinterpret_cast<const i4_t*>(
                qwd + (size_t)n * 256 + 192 + 16 * lgp);
        }

    bool act = (lgp == 0);
    // act-lane cells: (m=0..1, jt=0..1) at col j = 32w + 16jt + l15
    float swv[4][2];   // [gt][jt]
#pragma unroll
    for (int gt = 0; gt < 4; ++gt)
#pragma unroll
        for (int jt = 0; jt < 2; ++jt)
            swv[gt][jt] = sw[d * 1024 + 256 * gt + 32 * w + 16 * jt + l15];

    float c[2][2];     // [jt][m]
#pragma unroll
    for (int jt = 0; jt < 2; ++jt)
#pragma unroll
        for (int m = 0; m < 2; ++m)
            c[jt][m] = c0[((size_t)d * 32 + b2 * 2 + m) * 256 + 32 * w + 16 * jt + l15];

    // h0: block amax -> step-0 scale, quantize into parity-1 (all 512 lanes, 1 elem each)
    int im = l >> 5, ij = 32 * w + (l & 31);
    float v0 = h0[((size_t)d * 32 + b2 * 2 + im) * 256 + ij];
    float am = fabsf(v0);
#pragma unroll
    for (int off = 1; off < 64; off <<= 1)
        am = fmaxf(am, __shfl_xor(am, off));
    if (l == 0) red_sh[w] = am;
    __syncthreads();
    float bmax = red_sh[0];
#pragma unroll
    for (int q = 1; q < 8; ++q) bmax = fmaxf(bmax, red_sh[q]);
    bmax = fmaxf(bmax, 1e-20f);
    float s0 = bmax / 127.f;
    h8[1][im][ij] = (signed char)(int)__builtin_rintf(v0 * (127.f / bmax));

    float dq[4][2];
#pragma unroll
    for (int gt = 0; gt < 4; ++gt)
#pragma unroll
        for (int jt = 0; jt < 2; ++jt) dq[gt][jt] = swv[gt][jt] * s0;

    // ---- streaming pointers (t monotone) ----
    int t0 = d ? 1023 : 0;
    int xinc = d ? -2048 : 2048;
    int hinc = d ? -512 : 512;
    const unsigned short* xq = xg4 + ((size_t)(d * 16 + b2) * 1024 + t0) * 2048
                               + 32 * w + l15;          // + m*1024 + 256*gt + 16*jt
    unsigned short* hs0 = hs + ((size_t)(b2 * 2 + 0) * 1024 + t0) * 512 + d * 256 + 32 * w + l15;
    unsigned short* hs1 = hs + ((size_t)(b2 * 2 + 1) * 1024 + t0) * 512 + d * 256 + 32 * w + l15;

    unsigned short xc[4][2][2], xn[4][2][2];   // [gt][jt][m]
    if (act) {
#pragma unroll
        for (int gt = 0; gt < 4; ++gt)
#pragma unroll
            for (int jt = 0; jt < 2; ++jt)
#pragma unroll
                for (int m = 0; m < 2; ++m)
                    xc[gt][jt][m] = xq[m * 1024 + 256 * gt + 16 * jt];
    }

    i4_t z4 = (i4_t){0, 0, 0, 0};
    asm volatile("" : "+v"(z4));   // persistent zero C-operand

    __syncthreads();   // weights staged + h(-1) ready

    for (int s = 0; s < 1024; ++s) {
        int rp = (s + 1) & 1, wp = s & 1;

        // prefetch next step's xg values
        if (s < 1023) {
            xq += xinc;
            if (act) {
#pragma unroll
                for (int gt = 0; gt < 4; ++gt)
#pragma unroll
                    for (int jt = 0; jt < 2; ++jt)
#pragma unroll
                        for (int m = 0; m < 2; ++m)
                            xn[gt][jt][m] = xq[m * 1024 + 256 * gt + 16 * jt];
            }
        }

        // A fragments (rows 0,1 broadcast-duplicated across 16 A-rows)
        i4_t a[4];
#pragma unroll
        for (int ks = 0; ks < 4; ++ks)
            a[ks] = *reinterpret_cast<const i4_t*>(&h8[rp][l15 & 1][64 * ks + 16 * lgp]);

        i4_t acc[4][2];
#pragma unroll
        for (int gt = 0; gt < 4; ++gt)
#pragma unroll
            for (int jt = 0; jt < 2; ++jt) {
                acc[gt][jt] = __builtin_amdgcn_mfma_i32_16x16x64_i8(
                    a[0], wreg[gt][jt][0], z4, 0, 0, 0);
#pragma unroll
                for (int ks = 1; ks < 3; ++ks)
                    acc[gt][jt] = __builtin_amdgcn_mfma_i32_16x16x64_i8(
                        a[ks], wreg[gt][jt][ks], acc[gt][jt], 0, 0, 0);
                i4_t b = wsh[(w * 8 + gt * 2 + jt) * 64 + l];
                acc[gt][jt] = __builtin_amdgcn_mfma_i32_16x16x64_i8(
                    a[3], b, acc[gt][jt], 0, 0, 0);
            }

        // in-lane epilogue: act lanes own rows 0,1 of D for all 4 gates
        if (act) {
#pragma unroll
            for (int jt = 0; jt < 2; ++jt)
#pragma unroll
                for (int m = 0; m < 2; ++m) {
                    float pi = dq[0][jt] * (float)acc[0][jt][m] + bf2f(xc[0][jt][m]);
                    float pf = dq[1][jt] * (float)acc[1][jt][m] + bf2f(xc[1][jt][m]);
                    float pg = dq[2][jt] * (float)acc[2][jt][m] + bf2f(xc[2][jt][m]);
                    float po = dq[3][jt] * (float)acc[3][jt][m] + bf2f(xc[3][jt][m]);
                    float iv = sigf(pi), fv = sigf(pf), ov = sigf(po);
                    float gv = tanh2_(pg);
                    float cn = fv * c[jt][m] + iv * gv;
                    c[jt][m] = cn;
                    float hv = ov * tanh2_(cn);
                    unsigned short hb = f2bf(hv);
                    if (m) *(hs1 + 16 * jt) = hb; else *(hs0 + 16 * jt) = hb;
                    h8[wp][m][32 * w + 16 * jt + l15] =
                        (signed char)(int)__builtin_rintf(hv * 127.f);
                }
        }
        hs0 += hinc; hs1 += hinc;

        if (s == 0) {
#pragma unroll
            for (int gt = 0; gt < 4; ++gt)
#pragma unroll
                for (int jt = 0; jt < 2; ++jt) dq[gt][jt] = swv[gt][jt] * (1.f / 127.f);
        }
        if (act) {
#pragma unroll
            for (int gt = 0; gt < 4; ++gt)
#pragma unroll
                for (int jt = 0; jt < 2; ++jt)
#pragma unroll
                    for (int m = 0; m < 2; ++m) xc[gt][jt][m] = xn[gt][jt][m];
        }

        // single barrier: h8[wp] complete for next step (LDS drain only)
        asm volatile("s_waitcnt lgkmcnt(0)" ::: "memory");
        __builtin_amdgcn_sched_barrier(0);
        __builtin_amdgcn_s_barrier();
    }
}

// ---------------- logits = hs @ Wout^T + b_out (N padded to 16) ----------------
__global__ __launch_bounds__(256) void logits_kernel(const unsigned short* hs,
        const unsigned short* wout_bf, const float* b_out, float* logits) {
    int w = threadIdx.x >> 6, l = threadIdx.x & 63, l15 = l & 15, lgp = l >> 4;
    int mt = blockIdx.x * 4 + w;         // 0..2047
    const unsigned short* arow = hs + (size_t)(16 * mt + l15) * 512 + 8 * lgp;
    const unsigned short* brow = wout_bf + (size_t)l15 * 512 + 8 * lgp;
    f4_t acc; acc[0] = 0.f; acc[1] = 0.f; acc[2] = 0.f; acc[3] = 0.f;
#pragma unroll
    for (int ks = 0; ks < 16; ++ks) {
        bf8_t a = *reinterpret_cast<const bf8_t*>(arow + 32 * ks);
        bf8_t b = *reinterpret_cast<const bf8_t*>(brow + 32 * ks);
        acc = mfma16(a, b, acc);
    }
    float bo = (l15 < NTAG) ? b_out[l15] : 0.0f;
#pragma unroll
    for (int r = 0; r < 4; ++r) {
        int bt = 16 * mt + 4 * lgp + r;
        logits[(size_t)bt * 16 + l15] = acc[r] + bo;
    }
}

// ---------------- Viterbi: one wave per sequence; tree argmax ----------------
__global__ __launch_bounds__(64) void viterbi_kernel(const float* logits, const float* crf,
                                                     float* out) {
    int b = blockIdx.x, j = threadIdx.x;
    __shared__ unsigned char bp[1024][16];
    __shared__ unsigned char pth[1024];
    float crfj[NTAG];
#pragma unroll
    for (int i = 0; i < NTAG; ++i)
        crfj[i] = (j < NTAG) ? crf[i * NTAG + j] : 0.0f;
    const float* lgt = logits + (size_t)b * 1024 * 16;
    float v = (j < NTAG) ? lgt[j] : -3.0e38f;
    float lt_nxt = (j < NTAG) ? lgt[16 + j] : 0.0f;
    for (int t = 1; t < 1024; ++t) {
        float lt = lt_nxt;
        if (t < 1023) lt_nxt = (j < NTAG) ? lgt[(t + 1) * 16 + j] : 0.0f;
        float sv[NTAG];
#pragma unroll
        for (int i = 0; i < NTAG; ++i)
            sv[i] = __shfl(v, i) + crfj[i];
        // tree argmax (lowest index wins on ties: right only if strictly >)
        float av[7]; int ai[7];
#pragma unroll
        for (int i = 0; i < 7; ++i) {
            bool rgt = sv[2 * i + 1] > sv[2 * i];
            av[i] = rgt ? sv[2 * i + 1] : sv[2 * i];
            ai[i] = rgt ? 2 * i + 1 : 2 * i;
        }
        float bv[4]; int bi[4];
#pragma unroll
        for (int i = 0; i < 3; ++i) {
            bool rgt = av[2 * i + 1] > av[2 * i];
            bv[i] = rgt ? av[2 * i + 1] : av[2 * i];
            bi[i] = rgt ? ai[2 * i + 1] : ai[2 * i];
        }
        bv[3] = av[6]; bi[3] = ai[6];
        float cv0 = (bv[1] > bv[0]) ? bv[1] : bv[0];
        int   ci0 = (bv[1] > bv[0]) ? bi[1] : bi[0];
        float cv1 = (bv[3] > bv[2]) ? bv[3] : bv[2];
        int   ci1 = (bv[3] > bv[2]) ? bi[3] : bi[2];
        float best = (cv1 > cv0) ? cv1 : cv0;
        int   arg  = (cv1 > cv0) ? ci1 : ci0;
        v = (j < NTAG) ? (lt + best) : -3.0e38f;
        if (j < 16) bp[t][j] = (unsigned char)arg;
    }
    float best = -3.0e38f; int tag = 0;
#pragma unroll
    for (int jj = 0; jj < NTAG; ++jj) {
        float s = __shfl(v, jj);
        if (s > best) { best = s; tag = jj; }
    }
    __syncthreads();
    if (j == 0) {
        out[b] = best;
        int tg = tag;
        pth[1023] = (unsigned char)tg;
        for (int t = 1023; t >= 1; --t) {
            tg = bp[t][tg];
            pth[t - 1] = (unsigned char)tg;
        }
    }
    __syncthreads();
    float* pout = out + 32 + (size_t)b * 1024;
    for (int t = j; t < 1024; t += 64)
        pout[t] = (float)pth[t];
}

extern "C" void kernel_launch(void* const* d_in, const int* in_sizes, int n_in,
                              void* d_out, int out_size, void* d_ws, size_t ws_size,
                              hipStream_t stream) {
    const int* sent = (const int*)d_in[0];
    const float* emb = (const float*)d_in[1];
    const float* wih_f = (const float*)d_in[2];
    const float* whh_f = (const float*)d_in[3];
    const float* bih_f = (const float*)d_in[4];
    const float* bhh_f = (const float*)d_in[5];
    const float* wih_b = (const float*)d_in[6];
    const float* whh_b = (const float*)d_in[7];
    const float* bih_b = (const float*)d_in[8];
    const float* bhh_b = (const float*)d_in[9];
    const float* h0 = (const float*)d_in[10];
    const float* c0 = (const float*)d_in[11];
    const float* wout = (const float*)d_in[12];
    const float* b_out = (const float*)d_in[13];
    const float* crf = (const float*)d_in[14];

    char* ws = (char*)d_ws;
    signed char* qw       = (signed char*)(ws + 0);               // 512 KiB
    float* sw             = (float*)(ws + 524288);                // 8 KiB
    unsigned short* wih_bf = (unsigned short*)(ws + 1048576);     // 1 MiB
    float* biasc          = (float*)(ws + 2097152);               // 8 KiB
    unsigned short* wout_bf = (unsigned short*)(ws + 2105344);    // 16 KiB
    unsigned short* xbf   = (unsigned short*)(ws + 2121728);      // 16 MiB
    unsigned short* xg4   = (unsigned short*)(ws + 18898944);     // 128 MiB
    unsigned short* hs    = (unsigned short*)(ws + 153116672);    // 32 MiB
    float* logits         = (float*)(ws + 186671104);             // 2 MiB
    float* out = (float*)d_out;

    hipLaunchKernelGGL(prep_kernel, dim3(2088), dim3(256), 0, stream,
                       wih_f, wih_b, bih_f, bhh_f, bih_b, bhh_b, wout,
                       wih_bf, biasc, wout_bf);
    hipLaunchKernelGGL(wquant_kernel, dim3(512), dim3(256), 0, stream,
                       whh_f, whh_b, qw, sw);
    hipLaunchKernelGGL(embed_kernel, dim3(8192), dim3(256), 0, stream, sent, emb, xbf);
    hipLaunchKernelGGL(xproj_kernel, dim3(64, 16), dim3(256), 0, stream,
                       xbf, wih_bf, biasc, xg4);
    hipLaunchKernelGGL(lstm_kernel, dim3(32), dim3(512), 0, stream,
                       xg4, qw, sw, h0, c0, hs);
    hipLaunchKernelGGL(logits_kernel, dim3(512), dim3(256), 0, stream,
                       hs, wout_bf, b_out, logits);
    hipLaunchKernelGGL(viterbi_kernel, dim3(32), dim3(64), 0, stream, logits, crf, out);
}

// Round 10
// 1541.160 us; speedup vs baseline: 1.8288x; 1.8288x over previous
//
#include <hip/hip_runtime.h>
#include <hip/hip_bf16.h>
#include <cstdint>

#define B_ 32
#define T_ 1024
#define E_ 256
#define H_ 256
#define G_ 1024
#define NTAG 14

typedef __bf16 bf8_t __attribute__((ext_vector_type(8)));
typedef float f4_t __attribute__((ext_vector_type(4)));
typedef int i4_t __attribute__((ext_vector_type(4)));
typedef unsigned short u16x4 __attribute__((ext_vector_type(4)));

__device__ __forceinline__ unsigned short f2bf(float f) {
    unsigned u = __builtin_bit_cast(unsigned, f);
    u = u + 0x7FFFu + ((u >> 16) & 1u);
    return (unsigned short)(u >> 16);
}
__device__ __forceinline__ float bf2f(unsigned short s) {
    unsigned u = ((unsigned)s) << 16;
    return __builtin_bit_cast(float, u);
}
__device__ __forceinline__ float sigf(float x) { return 1.0f / (1.0f + __expf(-x)); }
// branch-free tanh: overflow-safe (exp->inf => 1; exp->0 => -1)
__device__ __forceinline__ float tanh2_(float x) {
    float e = __expf(2.0f * x);
    return 1.0f - 2.0f / (e + 1.0f);
}
__device__ __forceinline__ f4_t mfma16(bf8_t a, bf8_t b, f4_t c) {
    return __builtin_amdgcn_mfma_f32_16x16x32_bf16(a, b, c, 0, 0, 0);
}

// ---------------- prep: wih->bf16, combine biases, wout pad ----------------
__global__ __launch_bounds__(256) void prep_kernel(
        const float* wih_f, const float* wih_b,
        const float* bih_f, const float* bhh_f,
        const float* bih_b, const float* bhh_b,
        const float* wout,
        unsigned short* wih_bf, float* biasc, unsigned short* wout_bf) {
    int tid = blockIdx.x * 256 + threadIdx.x;
    if (tid < 524288) {                       // 2 x 262144: [d][1024][256]
        int d = tid >> 18, off = tid & 262143;
        wih_bf[tid] = f2bf((d ? wih_b : wih_f)[off]);
        return;
    }
    int t2 = tid - 524288;
    if (t2 < 8192) {                          // wout padded [16][512]
        int n = t2 >> 9, k = t2 & 511;
        wout_bf[t2] = (n < NTAG) ? f2bf(wout[n * 512 + k]) : (unsigned short)0;
        return;
    }
    int t3 = t2 - 8192;
    if (t3 < 2048) {                          // biasc [2][1024]
        int d = t3 >> 10, g = t3 & 1023;
        biasc[t3] = d ? (bih_b[g] + bhh_b[g]) : (bih_f[g] + bhh_f[g]);
    }
}

// ---------------- whh -> int8 with per-row scale ----------------
__global__ __launch_bounds__(256) void wquant_kernel(const float* whh_f, const float* whh_b,
                                                     signed char* qw, float* sw) {
    int row = blockIdx.x * 4 + (threadIdx.x >> 6);   // 0..2047 = [d][1024]
    int l = threadIdx.x & 63;
    int d = row >> 10, rr = row & 1023;
    const float* src = (d ? whh_b : whh_f) + (size_t)rr * 256;
    float4 v = *reinterpret_cast<const float4*>(src + 4 * l);
    float am = fmaxf(fmaxf(fabsf(v.x), fabsf(v.y)), fmaxf(fabsf(v.z), fabsf(v.w)));
#pragma unroll
    for (int off = 1; off < 64; off <<= 1)
        am = fmaxf(am, __shfl_xor(am, off));
    am = fmaxf(am, 1e-20f);
    float inv = 127.f / am;
    int q0 = (int)__builtin_rintf(v.x * inv), q1 = (int)__builtin_rintf(v.y * inv);
    int q2 = (int)__builtin_rintf(v.z * inv), q3 = (int)__builtin_rintf(v.w * inv);
    unsigned u = (q0 & 255) | ((q1 & 255) << 8) | ((q2 & 255) << 16) | ((q3 & 255) << 24);
    *reinterpret_cast<unsigned*>(qw + (size_t)row * 256 + 4 * l) = u;
    if (l == 0) sw[row] = am / 127.f;
}

// ---------------- embedding gather -> bf16 ----------------
__global__ __launch_bounds__(256) void embed_kernel(const int* sent, const float* emb,
                                                    unsigned short* xbf) {
    int tid = blockIdx.x * 256 + threadIdx.x; // 32768*64 threads
    int bt = tid >> 6;
    int e0 = (tid & 63) << 2;
    int tok = sent[bt];
    float4 v = *reinterpret_cast<const float4*>(emb + (size_t)tok * E_ + e0);
    u16x4 o;
    o[0] = f2bf(v.x); o[1] = f2bf(v.y); o[2] = f2bf(v.z); o[3] = f2bf(v.w);
    *reinterpret_cast<u16x4*>(xbf + (size_t)bt * E_ + e0) = o;
}

// ---- input projection -> xg4[d*16+b2][t][m 2][1024 n]; B pinned in regs, 16-t loop ----
__global__ __launch_bounds__(256, 1) void xproj_kernel(const unsigned short* xbf,
        const unsigned short* wih_bf, const float* biasc, unsigned short* xg4) {
    int tt = blockIdx.x;                 // 0..63 (16 t each)
    int y = blockIdx.y;                  // d*8 + bh*4 + ns
    int ns = y & 3, bh = (y >> 2) & 1, d = y >> 3;
    int w = threadIdx.x >> 6, l = threadIdx.x & 63;
    int l15 = l & 15, lgp = l >> 4;
    __shared__ unsigned short sh[256][16];

    // B fragments: this wave's 64 n-cols x 256 k, resident for the whole t-loop
    int nbase = ns * 256 + w * 64;
    const unsigned short* wd = wih_bf + (size_t)d * 262144;
    bf8_t breg[4][8];
    float bias[4];
#pragma unroll
    for (int p = 0; p < 4; ++p) {
        int n = nbase + 16 * p + l15;
        bias[p] = biasc[d * G_ + n];
        const unsigned short* brow = wd + (size_t)n * E_ + 8 * lgp;
#pragma unroll
        for (int ks = 0; ks < 8; ++ks)
            breg[p][ks] = *reinterpret_cast<const bf8_t*>(brow + 32 * ks);
    }
#pragma unroll
    for (int p = 0; p < 4; ++p)
#pragma unroll
        for (int ks = 0; ks < 8; ++ks)
            asm volatile("" : "+v"(breg[p][ks]));

    const unsigned short* arow =
        xbf + ((size_t)(16 * bh + l15) * 1024 + tt * 16) * E_ + 8 * lgp;

    for (int it = 0; it < 16; ++it) {
        int t = tt * 16 + it;
        bf8_t a[8];
#pragma unroll
        for (int ks = 0; ks < 8; ++ks)
            a[ks] = *reinterpret_cast<const bf8_t*>(arow + 32 * ks);
        arow += 256;

        f4_t acc[4];
#pragma unroll
        for (int p = 0; p < 4; ++p) { acc[p][0] = 0.f; acc[p][1] = 0.f; acc[p][2] = 0.f; acc[p][3] = 0.f; }
#pragma unroll
        for (int p = 0; p < 4; ++p)
#pragma unroll
            for (int ks = 0; ks < 8; ++ks)
                acc[p] = mfma16(a[ks], breg[p][ks], acc[p]);

#pragma unroll
        for (int p = 0; p < 4; ++p)
#pragma unroll
            for (int r = 0; r < 4; ++r)
                sh[w * 64 + 16 * p + l15][4 * lgp + r] = f2bf(acc[p][r] + bias[p]);
        __syncthreads();
        // writeout: thread q owns n = ns*256+q; coalesced 2B stores
        int q = threadIdx.x;
#pragma unroll
        for (int p = 0; p < 8; ++p) {
            int b2g = 8 * bh + p;
            size_t base = ((size_t)(d * 16 + b2g) * 1024 + t) * 2048 + ns * 256 + q;
            xg4[base]        = sh[q][2 * p];      // m=0
            xg4[base + 1024] = sh[q][2 * p + 1];  // m=1
        }
        __syncthreads();   // protect sh reuse next iteration
    }
}

// ------- recurrence: 32 WGs = (dir, batch-pair); broadcast-redundant epilogue ----
// A rows duplicate h (row r = batch m=r&1) => every lane's acc elems {0,1} hold
// cells (m=0,1) at its col. Lane (lgp,l15) owns cell (jt=lgp&1, m=lgp>>1): pure
// in-register select, no cross-lane traffic, 1 barrier/step.
__global__ __launch_bounds__(512, 2) void lstm_kernel(const unsigned short* xg4,
        const signed char* qw, const float* sw, const float* h0, const float* c0,
        unsigned short* hs) {
    int bid = blockIdx.x;            // 0..31
    int b2 = bid & 15, d = bid >> 4;
    int tid = threadIdx.x;
    int w = tid >> 6, l = tid & 63, l15 = l & 15, lgp = l >> 4;

    __shared__ __attribute__((aligned(16))) signed char h8[2][2][320]; // parity x m x col
    __shared__ i4_t wsh[4096];       // 64 KiB: ks=3 weight quarter
    __shared__ float red_sh[8];

    const signed char* qwd = qw + (size_t)d * 262144;

    // ks 0..2 weights -> registers (24 quads = 96 regs)
    i4_t wreg[4][2][3];
#pragma unroll
    for (int gt = 0; gt < 4; ++gt)
#pragma unroll
        for (int jt = 0; jt < 2; ++jt) {
            int n = 256 * gt + 32 * w + 16 * jt + l15;
#pragma unroll
            for (int ks = 0; ks < 3; ++ks)
                wreg[gt][jt][ks] = *reinterpret_cast<const i4_t*>(
                    qwd + (size_t)n * 256 + 64 * ks + 16 * lgp);
        }
#pragma unroll
    for (int gt = 0; gt < 4; ++gt)
#pragma unroll
        for (int jt = 0; jt < 2; ++jt)
#pragma unroll
            for (int ks = 0; ks < 3; ++ks)
                asm volatile("" : "+v"(wreg[gt][jt][ks]));   // keep resident

    // ks=3 weights -> LDS
#pragma unroll
    for (int gt = 0; gt < 4; ++gt)
#pragma unroll
        for (int jt = 0; jt < 2; ++jt) {
            int n = 256 * gt + 32 * w + 16 * jt + l15;
            wsh[(w * 8 + gt * 2 + jt) * 64 + l] = *reinterpret_cast<const i4_t*>(
                qwd + (size_t)n * 256 + 192 + 16 * lgp);
        }

    // ---- this lane's cell ----
    int jt_c = lgp & 1, m_c = lgp >> 1;
    int j = 32 * w + 16 * jt_c + l15;

    float swv[4];
#pragma unroll
    for (int gt = 0; gt < 4; ++gt)
        swv[gt] = sw[d * 1024 + 256 * gt + j];
    float c = c0[((size_t)d * 32 + b2 * 2 + m_c) * 256 + j];

    // h0: block amax -> step-0 scale, quantize into parity-1 (512 lanes, 1 elem each)
    int im = tid >> 8, ij = tid & 255;
    float v0 = h0[((size_t)d * 32 + b2 * 2 + im) * 256 + ij];
    float am = fabsf(v0);
#pragma unroll
    for (int off = 1; off < 64; off <<= 1)
        am = fmaxf(am, __shfl_xor(am, off));
    if (l == 0) red_sh[w] = am;
    __syncthreads();
    float bmax = red_sh[0];
#pragma unroll
    for (int q = 1; q < 8; ++q) bmax = fmaxf(bmax, red_sh[q]);
    bmax = fmaxf(bmax, 1e-20f);
    float s0 = bmax / 127.f;
    h8[1][im][ij] = (signed char)(int)__builtin_rintf(v0 * (127.f / bmax));

    float dq[4];
#pragma unroll
    for (int gt = 0; gt < 4; ++gt) dq[gt] = swv[gt] * s0;

    // ---- streaming pointers (t monotone) ----
    int t0 = d ? 1023 : 0;
    int xinc = d ? -2048 : 2048;
    int hinc = d ? -512 : 512;
    const unsigned short* xq = xg4 + ((size_t)(d * 16 + b2) * 1024 + t0) * 2048
                               + m_c * 1024 + j;
    unsigned short* hsp = hs + ((size_t)(b2 * 2 + m_c) * 1024 + t0) * 512 + d * 256 + j;

    unsigned short xc[4], xn[4];
#pragma unroll
    for (int gt = 0; gt < 4; ++gt) xc[gt] = xq[256 * gt];

    i4_t z4 = (i4_t){0, 0, 0, 0};
    asm volatile("" : "+v"(z4));   // persistent zero C-operand

    __syncthreads();   // weights staged + h(-1) ready

    for (int s = 0; s < 1024; ++s) {
        int rp = (s + 1) & 1, wp = s & 1;

        // prefetch next step's xg values
        if (s < 1023) {
            xq += xinc;
#pragma unroll
            for (int gt = 0; gt < 4; ++gt) xn[gt] = xq[256 * gt];
        }

        // A fragments (row r = batch m=r&1 -> full redundancy across lgp groups)
        i4_t a[4];
#pragma unroll
        for (int ks = 0; ks < 4; ++ks)
            a[ks] = *reinterpret_cast<const i4_t*>(&h8[rp][l15 & 1][64 * ks + 16 * lgp]);

        i4_t acc[4][2];
#pragma unroll
        for (int gt = 0; gt < 4; ++gt)
#pragma unroll
            for (int jt = 0; jt < 2; ++jt) {
                acc[gt][jt] = __builtin_amdgcn_mfma_i32_16x16x64_i8(
                    a[0], wreg[gt][jt][0], z4, 0, 0, 0);
#pragma unroll
                for (int ks = 1; ks < 3; ++ks)
                    acc[gt][jt] = __builtin_amdgcn_mfma_i32_16x16x64_i8(
                        a[ks], wreg[gt][jt][ks], acc[gt][jt], 0, 0, 0);
                i4_t b = wsh[(w * 8 + gt * 2 + jt) * 64 + l];
                acc[gt][jt] = __builtin_amdgcn_mfma_i32_16x16x64_i8(
                    a[3], b, acc[gt][jt], 0, 0, 0);
            }

        // in-register select of this lane's cell (12 cndmask, no cross-lane)
        int gi[4];
#pragma unroll
        for (int gt = 0; gt < 4; ++gt) {
            int e0 = jt_c ? acc[gt][1][0] : acc[gt][0][0];   // m=0 copy
            int e1 = jt_c ? acc[gt][1][1] : acc[gt][0][1];   // m=1 copy
            gi[gt] = m_c ? e1 : e0;
        }

        // epilogue: every lane computes its one cell
        float pi = dq[0] * (float)gi[0] + bf2f(xc[0]);
        float pf = dq[1] * (float)gi[1] + bf2f(xc[1]);
        float pg = dq[2] * (float)gi[2] + bf2f(xc[2]);
        float po = dq[3] * (float)gi[3] + bf2f(xc[3]);
        float iv = sigf(pi), fv = sigf(pf), ov = sigf(po);
        float gv = tanh2_(pg);
        float cn = fv * c + iv * gv;
        c = cn;
        float hv = ov * tanh2_(cn);
        *hsp = f2bf(hv);
        hsp += hinc;
        h8[wp][m_c][j] = (signed char)(int)__builtin_rintf(hv * 127.f);

        if (s == 0) {
#pragma unroll
            for (int gt = 0; gt < 4; ++gt) dq[gt] = swv[gt] * (1.f / 127.f);
        }
#pragma unroll
        for (int gt = 0; gt < 4; ++gt) xc[gt] = xn[gt];

        // single barrier: h8[wp] complete for next step (LDS drain only)
        asm volatile("s_waitcnt lgkmcnt(0)" ::: "memory");
        __builtin_amdgcn_sched_barrier(0);
        __builtin_amdgcn_s_barrier();
    }
}

// ---------------- logits = hs @ Wout^T + b_out (N padded to 16) ----------------
__global__ __launch_bounds__(256) void logits_kernel(const unsigned short* hs,
        const unsigned short* wout_bf, const float* b_out, float* logits) {
    int w = threadIdx.x >> 6, l = threadIdx.x & 63, l15 = l & 15, lgp = l >> 4;
    int mt = blockIdx.x * 4 + w;         // 0..2047
    const unsigned short* arow = hs + (size_t)(16 * mt + l15) * 512 + 8 * lgp;
    const unsigned short* brow = wout_bf + (size_t)l15 * 512 + 8 * lgp;
    f4_t acc; acc[0] = 0.f; acc[1] = 0.f; acc[2] = 0.f; acc[3] = 0.f;
#pragma unroll
    for (int ks = 0; ks < 16; ++ks) {
        bf8_t a = *reinterpret_cast<const bf8_t*>(arow + 32 * ks);
        bf8_t b = *reinterpret_cast<const bf8_t*>(brow + 32 * ks);
        acc = mfma16(a, b, acc);
    }
    float bo = (l15 < NTAG) ? b_out[l15] : 0.0f;
#pragma unroll
    for (int r = 0; r < 4; ++r) {
        int bt = 16 * mt + 4 * lgp + r;
        logits[(size_t)bt * 16 + l15] = acc[r] + bo;
    }
}

// ---------------- Viterbi: one wave per sequence; tree argmax ----------------
__global__ __launch_bounds__(64) void viterbi_kernel(const float* logits, const float* crf,
                                                     float* out) {
    int b = blockIdx.x, j = threadIdx.x;
    __shared__ unsigned char bp[1024][16];
    __shared__ unsigned char pth[1024];
    float crfj[NTAG];
#pragma unroll
    for (int i = 0; i < NTAG; ++i)
        crfj[i] = (j < NTAG) ? crf[i * NTAG + j] : 0.0f;
    const float* lgt = logits + (size_t)b * 1024 * 16;
    float v = (j < NTAG) ? lgt[j] : -3.0e38f;
    float lt_nxt = (j < NTAG) ? lgt[16 + j] : 0.0f;
    for (int t = 1; t < 1024; ++t) {
        float lt = lt_nxt;
        if (t < 1023) lt_nxt = (j < NTAG) ? lgt[(t + 1) * 16 + j] : 0.0f;
        float sv[NTAG];
#pragma unroll
        for (int i = 0; i < NTAG; ++i)
            sv[i] = __shfl(v, i) + crfj[i];
        // tree argmax (lowest index wins on ties: right only if strictly >)
        float av[7]; int ai[7];
#pragma unroll
        for (int i = 0; i < 7; ++i) {
            bool rgt = sv[2 * i + 1] > sv[2 * i];
            av[i] = rgt ? sv[2 * i + 1] : sv[2 * i];
            ai[i] = rgt ? 2 * i + 1 : 2 * i;
        }
        float bv[4]; int bi[4];
#pragma unroll
        for (int i = 0; i < 3; ++i) {
            bool rgt = av[2 * i + 1] > av[2 * i];
            bv[i] = rgt ? av[2 * i + 1] : av[2 * i];
            bi[i] = rgt ? ai[2 * i + 1] : ai[2 * i];
        }
        bv[3] = av[6]; bi[3] = ai[6];
        float cv0 = (bv[1] > bv[0]) ? bv[1] : bv[0];
        int   ci0 = (bv[1] > bv[0]) ? bi[1] : bi[0];
        float cv1 = (bv[3] > bv[2]) ? bv[3] : bv[2];
        int   ci1 = (bv[3] > bv[2]) ? bi[3] : bi[2];
        float best = (cv1 > cv0) ? cv1 : cv0;
        int   arg  = (cv1 > cv0) ? ci1 : ci0;
        v = (j < NTAG) ? (lt + best) : -3.0e38f;
        if (j < 16) bp[t][j] = (unsigned char)arg;
    }
    float best = -3.0e38f; int tag = 0;
#pragma unroll
    for (int jj = 0; jj < NTAG; ++jj) {
        float s = __shfl(v, jj);
        if (s > best) { best = s; tag = jj; }
    }
    __syncthreads();
    if (j == 0) {
        out[b] = best;
        int tg = tag;
        pth[1023] = (unsigned char)tg;
        for (int t = 1023; t >= 1; --t) {
            tg = bp[t][tg];
            pth[t - 1] = (unsigned char)tg;
        }
    }
    __syncthreads();
    float* pout = out + 32 + (size_t)b * 1024;
    for (int t = j; t < 1024; t += 64)
        pout[t] = (float)pth[t];
}

extern "C" void kernel_launch(void* const* d_in, const int* in_sizes, int n_in,
                              void* d_out, int out_size, void* d_ws, size_t ws_size,
                              hipStream_t stream) {
    const int* sent = (const int*)d_in[0];
    const float* emb = (const float*)d_in[1];
    const float* wih_f = (const float*)d_in[2];
    const float* whh_f = (const float*)d_in[3];
    const float* bih_f = (const float*)d_in[4];
    const float* bhh_f = (const float*)d_in[5];
    const float* wih_b = (const float*)d_in[6];
    const float* whh_b = (const float*)d_in[7];
    const float* bih_b = (const float*)d_in[8];
    const float* bhh_b = (const float*)d_in[9];
    const float* h0 = (const float*)d_in[10];
    const float* c0 = (const float*)d_in[11];
    const float* wout = (const float*)d_in[12];
    const float* b_out = (const float*)d_in[13];
    const float* crf = (const float*)d_in[14];

    char* ws = (char*)d_ws;
    signed char* qw       = (signed char*)(ws + 0);               // 512 KiB
    float* sw             = (float*)(ws + 524288);                // 8 KiB
    unsigned short* wih_bf = (unsigned short*)(ws + 1048576);     // 1 MiB
    float* biasc          = (float*)(ws + 2097152);               // 8 KiB
    unsigned short* wout_bf = (unsigned short*)(ws + 2105344);    // 16 KiB
    unsigned short* xbf   = (unsigned short*)(ws + 2121728);      // 16 MiB
    unsigned short* xg4   = (unsigned short*)(ws + 18898944);     // 128 MiB
    unsigned short* hs    = (unsigned short*)(ws + 153116672);    // 32 MiB
    float* logits         = (float*)(ws + 186671104);             // 2 MiB
    float* out = (float*)d_out;

    hipLaunchKernelGGL(prep_kernel, dim3(2088), dim3(256), 0, stream,
                       wih_f, wih_b, bih_f, bhh_f, bih_b, bhh_b, wout,
                       wih_bf, biasc, wout_bf);
    hipLaunchKernelGGL(wquant_kernel, dim3(512), dim3(256), 0, stream,
                       whh_f, whh_b, qw, sw);
    hipLaunchKernelGGL(embed_kernel, dim3(8192), dim3(256), 0, stream, sent, emb, xbf);
    hipLaunchKernelGGL(xproj_kernel, dim3(64, 16), dim3(256), 0, stream,
                       xbf, wih_bf, biasc, xg4);
    hipLaunchKernelGGL(lstm_kernel, dim3(32), dim3(512), 0, stream,
                       xg4, qw, sw, h0, c0, hs);
    hipLaunchKernelGGL(logits_kernel, dim3(512), dim3(256), 0, stream,
                       hs, wout_bf, b_out, logits);
    hipLaunchKernelGGL(viterbi_kernel, dim3(32), dim3(64), 0, stream, logits, crf, out);
}

// Round 11
// 1490.824 us; speedup vs baseline: 1.8905x; 1.0338x over previous
//
#include <hip/hip_runtime.h>
#include <hip/hip_bf16.h>
#include <cstdint>

#define B_ 32
#define T_ 1024
#define E_ 256
#define H_ 256
#define G_ 1024
#define NTAG 14

typedef __bf16 bf8_t __attribute__((ext_vector_type(8)));
typedef float f4_t __attribute__((ext_vector_type(4)));
typedef int i4_t __attribute__((ext_vector_type(4)));
typedef unsigned short u16x4 __attribute__((ext_vector_type(4)));

__device__ __forceinline__ unsigned short f2bf(float f) {
    unsigned u = __builtin_bit_cast(unsigned, f);
    u = u + 0x7FFFu + ((u >> 16) & 1u);
    return (unsigned short)(u >> 16);
}
__device__ __forceinline__ float bf2f(unsigned short s) {
    unsigned u = ((unsigned)s) << 16;
    return __builtin_bit_cast(float, u);
}
__device__ __forceinline__ float sigf(float x) { return 1.0f / (1.0f + __expf(-x)); }
// branch-free tanh: overflow-safe (exp->inf => 1; exp->0 => -1)
__device__ __forceinline__ float tanh2_(float x) {
    float e = __expf(2.0f * x);
    return 1.0f - 2.0f / (e + 1.0f);
}
__device__ __forceinline__ f4_t mfma16(bf8_t a, bf8_t b, f4_t c) {
    return __builtin_amdgcn_mfma_f32_16x16x32_bf16(a, b, c, 0, 0, 0);
}

// ---------------- prep: wih->bf16, combine biases, wout pad ----------------
__global__ __launch_bounds__(256) void prep_kernel(
        const float* wih_f, const float* wih_b,
        const float* bih_f, const float* bhh_f,
        const float* bih_b, const float* bhh_b,
        const float* wout,
        unsigned short* wih_bf, float* biasc, unsigned short* wout_bf) {
    int tid = blockIdx.x * 256 + threadIdx.x;
    if (tid < 524288) {                       // 2 x 262144: [d][1024][256]
        int d = tid >> 18, off = tid & 262143;
        wih_bf[tid] = f2bf((d ? wih_b : wih_f)[off]);
        return;
    }
    int t2 = tid - 524288;
    if (t2 < 8192) {                          // wout padded [16][512]
        int n = t2 >> 9, k = t2 & 511;
        wout_bf[t2] = (n < NTAG) ? f2bf(wout[n * 512 + k]) : (unsigned short)0;
        return;
    }
    int t3 = t2 - 8192;
    if (t3 < 2048) {                          // biasc [2][1024]
        int d = t3 >> 10, g = t3 & 1023;
        biasc[t3] = d ? (bih_b[g] + bhh_b[g]) : (bih_f[g] + bhh_f[g]);
    }
}

// ---------------- whh -> int8 with per-row scale ----------------
__global__ __launch_bounds__(256) void wquant_kernel(const float* whh_f, const float* whh_b,
                                                     signed char* qw, float* sw) {
    int row = blockIdx.x * 4 + (threadIdx.x >> 6);   // 0..2047 = [d][1024]
    int l = threadIdx.x & 63;
    int d = row >> 10, rr = row & 1023;
    const float* src = (d ? whh_b : whh_f) + (size_t)rr * 256;
    float4 v = *reinterpret_cast<const float4*>(src + 4 * l);
    float am = fmaxf(fmaxf(fabsf(v.x), fabsf(v.y)), fmaxf(fabsf(v.z), fabsf(v.w)));
#pragma unroll
    for (int off = 1; off < 64; off <<= 1)
        am = fmaxf(am, __shfl_xor(am, off));
    am = fmaxf(am, 1e-20f);
    float inv = 127.f / am;
    int q0 = (int)__builtin_rintf(v.x * inv), q1 = (int)__builtin_rintf(v.y * inv);
    int q2 = (int)__builtin_rintf(v.z * inv), q3 = (int)__builtin_rintf(v.w * inv);
    unsigned u = (q0 & 255) | ((q1 & 255) << 8) | ((q2 & 255) << 16) | ((q3 & 255) << 24);
    *reinterpret_cast<unsigned*>(qw + (size_t)row * 256 + 4 * l) = u;
    if (l == 0) sw[row] = am / 127.f;
}

// ---------------- embedding gather -> bf16 ----------------
__global__ __launch_bounds__(256) void embed_kernel(const int* sent, const float* emb,
                                                    unsigned short* xbf) {
    int tid = blockIdx.x * 256 + threadIdx.x; // 32768*64 threads
    int bt = tid >> 6;
    int e0 = (tid & 63) << 2;
    int tok = sent[bt];
    float4 v = *reinterpret_cast<const float4*>(emb + (size_t)tok * E_ + e0);
    u16x4 o;
    o[0] = f2bf(v.x); o[1] = f2bf(v.y); o[2] = f2bf(v.z); o[3] = f2bf(v.w);
    *reinterpret_cast<u16x4*>(xbf + (size_t)bt * E_ + e0) = o;
}

// ---- input projection -> xg4[d*16+b2][t][m 2][1024 n]; B pinned in regs, 16-t loop ----
__global__ __launch_bounds__(256, 1) void xproj_kernel(const unsigned short* xbf,
        const unsigned short* wih_bf, const float* biasc, unsigned short* xg4) {
    int tt = blockIdx.x;                 // 0..63 (16 t each)
    int y = blockIdx.y;                  // d*8 + bh*4 + ns
    int ns = y & 3, bh = (y >> 2) & 1, d = y >> 3;
    int w = threadIdx.x >> 6, l = threadIdx.x & 63;
    int l15 = l & 15, lgp = l >> 4;
    __shared__ unsigned short sh[256][16];

    // B fragments: this wave's 64 n-cols x 256 k, resident for the whole t-loop
    int nbase = ns * 256 + w * 64;
    const unsigned short* wd = wih_bf + (size_t)d * 262144;
    bf8_t breg[4][8];
    float bias[4];
#pragma unroll
    for (int p = 0; p < 4; ++p) {
        int n = nbase + 16 * p + l15;
        bias[p] = biasc[d * G_ + n];
        const unsigned short* brow = wd + (size_t)n * E_ + 8 * lgp;
#pragma unroll
        for (int ks = 0; ks < 8; ++ks)
            breg[p][ks] = *reinterpret_cast<const bf8_t*>(brow + 32 * ks);
    }
#pragma unroll
    for (int p = 0; p < 4; ++p)
#pragma unroll
        for (int ks = 0; ks < 8; ++ks)
            asm volatile("" : "+v"(breg[p][ks]));

    const unsigned short* arow =
        xbf + ((size_t)(16 * bh + l15) * 1024 + tt * 16) * E_ + 8 * lgp;

    for (int it = 0; it < 16; ++it) {
        int t = tt * 16 + it;
        bf8_t a[8];
#pragma unroll
        for (int ks = 0; ks < 8; ++ks)
            a[ks] = *reinterpret_cast<const bf8_t*>(arow + 32 * ks);
        arow += 256;

        f4_t acc[4];
#pragma unroll
        for (int p = 0; p < 4; ++p) { acc[p][0] = 0.f; acc[p][1] = 0.f; acc[p][2] = 0.f; acc[p][3] = 0.f; }
#pragma unroll
        for (int p = 0; p < 4; ++p)
#pragma unroll
            for (int ks = 0; ks < 8; ++ks)
                acc[p] = mfma16(a[ks], breg[p][ks], acc[p]);

#pragma unroll
        for (int p = 0; p < 4; ++p)
#pragma unroll
            for (int r = 0; r < 4; ++r)
                sh[w * 64 + 16 * p + l15][4 * lgp + r] = f2bf(acc[p][r] + bias[p]);
        __syncthreads();
        // writeout: thread q owns n = ns*256+q; coalesced 2B stores
        int q = threadIdx.x;
#pragma unroll
        for (int p = 0; p < 8; ++p) {
            int b2g = 8 * bh + p;
            size_t base = ((size_t)(d * 16 + b2g) * 1024 + t) * 2048 + ns * 256 + q;
            xg4[base]        = sh[q][2 * p];      // m=0
            xg4[base + 1024] = sh[q][2 * p + 1];  // m=1
        }
        __syncthreads();   // protect sh reuse next iteration
    }
}

// ------- recurrence: 32 WGs = (dir, batch-pair); ALL weights in regs, 1 barrier/step ----
// A rows duplicate h (row r = batch m=r&1) => every lane's acc elems {0,1} hold
// cells (m=0,1) at its col. Lane (lgp,l15) owns cell (jt=lgp&1, m=lgp>>1).
__global__ __launch_bounds__(512, 2) void lstm_kernel(const unsigned short* xg4,
        const signed char* qw, const float* sw, const float* h0, const float* c0,
        unsigned short* hs) {
    int bid = blockIdx.x;            // 0..31
    int b2 = bid & 15, d = bid >> 4;
    int tid = threadIdx.x;
    int w = tid >> 6, l = tid & 63, l15 = l & 15, lgp = l >> 4;

    __shared__ __attribute__((aligned(16))) signed char h8[2][2][320]; // parity x m x col
    __shared__ float red_sh[8];

    const signed char* qwd = qw + (size_t)d * 262144;

    // ALL weights -> registers: 32 quads = 128 regs/lane, pinned
    i4_t wreg[4][2][4];
#pragma unroll
    for (int gt = 0; gt < 4; ++gt)
#pragma unroll
        for (int jt = 0; jt < 2; ++jt) {
            int n = 256 * gt + 32 * w + 16 * jt + l15;
#pragma unroll
            for (int ks = 0; ks < 4; ++ks)
                wreg[gt][jt][ks] = *reinterpret_cast<const i4_t*>(
                    qwd + (size_t)n * 256 + 64 * ks + 16 * lgp);
        }
#pragma unroll
    for (int gt = 0; gt < 4; ++gt)
#pragma unroll
        for (int jt = 0; jt < 2; ++jt)
#pragma unroll
            for (int ks = 0; ks < 4; ++ks)
                asm volatile("" : "+v"(wreg[gt][jt][ks]));   // keep resident

    // ---- this lane's cell ----
    int jt_c = lgp & 1, m_c = lgp >> 1;
    int j = 32 * w + 16 * jt_c + l15;

    float swv[4];
#pragma unroll
    for (int gt = 0; gt < 4; ++gt)
        swv[gt] = sw[d * 1024 + 256 * gt + j];
    float c = c0[((size_t)d * 32 + b2 * 2 + m_c) * 256 + j];

    // h0: block amax -> step-0 scale, quantize into parity-1 (512 lanes, 1 elem each)
    int im = tid >> 8, ij = tid & 255;
    float v0 = h0[((size_t)d * 32 + b2 * 2 + im) * 256 + ij];
    float am = fabsf(v0);
#pragma unroll
    for (int off = 1; off < 64; off <<= 1)
        am = fmaxf(am, __shfl_xor(am, off));
    if (l == 0) red_sh[w] = am;
    __syncthreads();
    float bmax = red_sh[0];
#pragma unroll
    for (int q = 1; q < 8; ++q) bmax = fmaxf(bmax, red_sh[q]);
    bmax = fmaxf(bmax, 1e-20f);
    float s0 = bmax / 127.f;
    h8[1][im][ij] = (signed char)(int)__builtin_rintf(v0 * (127.f / bmax));

    float dq[4];
#pragma unroll
    for (int gt = 0; gt < 4; ++gt) dq[gt] = swv[gt] * s0;

    // ---- streaming pointers (t monotone) ----
    int t0 = d ? 1023 : 0;
    int xinc = d ? -2048 : 2048;
    int hinc = d ? -512 : 512;
    const unsigned short* xq = xg4 + ((size_t)(d * 16 + b2) * 1024 + t0) * 2048
                               + m_c * 1024 + j;
    unsigned short* hsp = hs + ((size_t)(b2 * 2 + m_c) * 1024 + t0) * 512 + d * 256 + j;

    unsigned short xc[4], xn[4];
#pragma unroll
    for (int gt = 0; gt < 4; ++gt) xc[gt] = xq[256 * gt];

    i4_t z4 = (i4_t){0, 0, 0, 0};
    asm volatile("" : "+v"(z4));   // persistent zero C-operand

    __syncthreads();   // h(-1) ready

    for (int s = 0; s < 1024; ++s) {
        int rp = (s + 1) & 1, wp = s & 1;

        // prefetch next step's xg values
        if (s < 1023) {
            xq += xinc;
#pragma unroll
            for (int gt = 0; gt < 4; ++gt) xn[gt] = xq[256 * gt];
        }

        // A fragments (row r = batch m=r&1 -> full redundancy across lgp groups)
        i4_t a[4];
#pragma unroll
        for (int ks = 0; ks < 4; ++ks)
            a[ks] = *reinterpret_cast<const i4_t*>(&h8[rp][l15 & 1][64 * ks + 16 * lgp]);

        i4_t acc[4][2];
#pragma unroll
        for (int gt = 0; gt < 4; ++gt)
#pragma unroll
            for (int jt = 0; jt < 2; ++jt) {
                acc[gt][jt] = __builtin_amdgcn_mfma_i32_16x16x64_i8(
                    a[0], wreg[gt][jt][0], z4, 0, 0, 0);
#pragma unroll
                for (int ks = 1; ks < 4; ++ks)
                    acc[gt][jt] = __builtin_amdgcn_mfma_i32_16x16x64_i8(
                        a[ks], wreg[gt][jt][ks], acc[gt][jt], 0, 0, 0);
            }

        // in-register select of this lane's cell (12 cndmask, no cross-lane)
        int gi[4];
#pragma unroll
        for (int gt = 0; gt < 4; ++gt) {
            int e0 = jt_c ? acc[gt][1][0] : acc[gt][0][0];   // m=0 copy
            int e1 = jt_c ? acc[gt][1][1] : acc[gt][0][1];   // m=1 copy
            gi[gt] = m_c ? e1 : e0;
        }

        // epilogue: every lane computes its one cell
        float pi = dq[0] * (float)gi[0] + bf2f(xc[0]);
        float pf = dq[1] * (float)gi[1] + bf2f(xc[1]);
        float pg = dq[2] * (float)gi[2] + bf2f(xc[2]);
        float po = dq[3] * (float)gi[3] + bf2f(xc[3]);
        float iv = sigf(pi), fv = sigf(pf), ov = sigf(po);
        float gv = tanh2_(pg);
        float cn = fv * c + iv * gv;
        c = cn;
        float hv = ov * tanh2_(cn);
        *hsp = f2bf(hv);
        hsp += hinc;
        h8[wp][m_c][j] = (signed char)(int)__builtin_rintf(hv * 127.f);

        if (s == 0) {
#pragma unroll
            for (int gt = 0; gt < 4; ++gt) dq[gt] = swv[gt] * (1.f / 127.f);
        }
#pragma unroll
        for (int gt = 0; gt < 4; ++gt) xc[gt] = xn[gt];

        // single barrier: h8[wp] complete for next step (tiny LDS drain)
        asm volatile("s_waitcnt lgkmcnt(0)" ::: "memory");
        __builtin_amdgcn_sched_barrier(0);
        __builtin_amdgcn_s_barrier();
    }
}

// ---------------- logits = hs @ Wout^T + b_out (N padded to 16) ----------------
__global__ __launch_bounds__(256) void logits_kernel(const unsigned short* hs,
        const unsigned short* wout_bf, const float* b_out, float* logits) {
    int w = threadIdx.x >> 6, l = threadIdx.x & 63, l15 = l & 15, lgp = l >> 4;
    int mt = blockIdx.x * 4 + w;         // 0..2047
    const unsigned short* arow = hs + (size_t)(16 * mt + l15) * 512 + 8 * lgp;
    const unsigned short* brow = wout_bf + (size_t)l15 * 512 + 8 * lgp;
    f4_t acc; acc[0] = 0.f; acc[1] = 0.f; acc[2] = 0.f; acc[3] = 0.f;
#pragma unroll
    for (int ks = 0; ks < 16; ++ks) {
        bf8_t a = *reinterpret_cast<const bf8_t*>(arow + 32 * ks);
        bf8_t b = *reinterpret_cast<const bf8_t*>(brow + 32 * ks);
        acc = mfma16(a, b, acc);
    }
    float bo = (l15 < NTAG) ? b_out[l15] : 0.0f;
#pragma unroll
    for (int r = 0; r < 4; ++r) {
        int bt = 16 * mt + 4 * lgp + r;
        logits[(size_t)bt * 16 + l15] = acc[r] + bo;
    }
}

// ---------------- Viterbi: one wave per sequence; tree argmax ----------------
__global__ __launch_bounds__(64) void viterbi_kernel(const float* logits, const float* crf,
                                                     float* out) {
    int b = blockIdx.x, j = threadIdx.x;
    __shared__ unsigned char bp[1024][16];
    __shared__ unsigned char pth[1024];
    float crfj[NTAG];
#pragma unroll
    for (int i = 0; i < NTAG; ++i)
        crfj[i] = (j < NTAG) ? crf[i * NTAG + j] : 0.0f;
    const float* lgt = logits + (size_t)b * 1024 * 16;
    float v = (j < NTAG) ? lgt[j] : -3.0e38f;
    float lt_nxt = (j < NTAG) ? lgt[16 + j] : 0.0f;
    for (int t = 1; t < 1024; ++t) {
        float lt = lt_nxt;
        if (t < 1023) lt_nxt = (j < NTAG) ? lgt[(t + 1) * 16 + j] : 0.0f;
        float sv[NTAG];
#pragma unroll
        for (int i = 0; i < NTAG; ++i)
            sv[i] = __shfl(v, i) + crfj[i];
        // tree argmax (lowest index wins on ties: right only if strictly >)
        float av[7]; int ai[7];
#pragma unroll
        for (int i = 0; i < 7; ++i) {
            bool rgt = sv[2 * i + 1] > sv[2 * i];
            av[i] = rgt ? sv[2 * i + 1] : sv[2 * i];
            ai[i] = rgt ? 2 * i + 1 : 2 * i;
        }
        float bv[4]; int bi[4];
#pragma unroll
        for (int i = 0; i < 3; ++i) {
            bool rgt = av[2 * i + 1] > av[2 * i];
            bv[i] = rgt ? av[2 * i + 1] : av[2 * i];
            bi[i] = rgt ? ai[2 * i + 1] : ai[2 * i];
        }
        bv[3] = av[6]; bi[3] = ai[6];
        float cv0 = (bv[1] > bv[0]) ? bv[1] : bv[0];
        int   ci0 = (bv[1] > bv[0]) ? bi[1] : bi[0];
        float cv1 = (bv[3] > bv[2]) ? bv[3] : bv[2];
        int   ci1 = (bv[3] > bv[2]) ? bi[3] : bi[2];
        float best = (cv1 > cv0) ? cv1 : cv0;
        int   arg  = (cv1 > cv0) ? ci1 : ci0;
        v = (j < NTAG) ? (lt + best) : -3.0e38f;
        if (j < 16) bp[t][j] = (unsigned char)arg;
    }
    float best = -3.0e38f; int tag = 0;
#pragma unroll
    for (int jj = 0; jj < NTAG; ++jj) {
        float s = __shfl(v, jj);
        if (s > best) { best = s; tag = jj; }
    }
    __syncthreads();
    if (j == 0) {
        out[b] = best;
        int tg = tag;
        pth[1023] = (unsigned char)tg;
        for (int t = 1023; t >= 1; --t) {
            tg = bp[t][tg];
            pth[t - 1] = (unsigned char)tg;
        }
    }
    __syncthreads();
    float* pout = out + 32 + (size_t)b * 1024;
    for (int t = j; t < 1024; t += 64)
        pout[t] = (float)pth[t];
}

extern "C" void kernel_launch(void* const* d_in, const int* in_sizes, int n_in,
                              void* d_out, int out_size, void* d_ws, size_t ws_size,
                              hipStream_t stream) {
    const int* sent = (const int*)d_in[0];
    const float* emb = (const float*)d_in[1];
    const float* wih_f = (const float*)d_in[2];
    const float* whh_f = (const float*)d_in[3];
    const float* bih_f = (const float*)d_in[4];
    const float* bhh_f = (const float*)d_in[5];
    const float* wih_b = (const float*)d_in[6];
    const float* whh_b = (const float*)d_in[7];
    const float* bih_b = (const float*)d_in[8];
    const float* bhh_b = (const float*)d_in[9];
    const float* h0 = (const float*)d_in[10];
    const float* c0 = (const float*)d_in[11];
    const float* wout = (const float*)d_in[12];
    const float* b_out = (const float*)d_in[13];
    const float* crf = (const float*)d_in[14];

    char* ws = (char*)d_ws;
    signed char* qw       = (signed char*)(ws + 0);               // 512 KiB
    float* sw             = (float*)(ws + 524288);                // 8 KiB
    unsigned short* wih_bf = (unsigned short*)(ws + 1048576);     // 1 MiB
    float* biasc          = (float*)(ws + 2097152);               // 8 KiB
    unsigned short* wout_bf = (unsigned short*)(ws + 2105344);    // 16 KiB
    unsigned short* xbf   = (unsigned short*)(ws + 2121728);      // 16 MiB
    unsigned short* xg4   = (unsigned short*)(ws + 18898944);     // 128 MiB
    unsigned short* hs    = (unsigned short*)(ws + 153116672);    // 32 MiB
    float* logits         = (float*)(ws + 186671104);             // 2 MiB
    float* out = (float*)d_out;

    hipLaunchKernelGGL(prep_kernel, dim3(2088), dim3(256), 0, stream,
                       wih_f, wih_b, bih_f, bhh_f, bih_b, bhh_b, wout,
                       wih_bf, biasc, wout_bf);
    hipLaunchKernelGGL(wquant_kernel, dim3(512), dim3(256), 0, stream,
                       whh_f, whh_b, qw, sw);
    hipLaunchKernelGGL(embed_kernel, dim3(8192), dim3(256), 0, stream, sent, emb, xbf);
    hipLaunchKernelGGL(xproj_kernel, dim3(64, 16), dim3(256), 0, stream,
                       xbf, wih_bf, biasc, xg4);
    hipLaunchKernelGGL(lstm_kernel, dim3(32), dim3(512), 0, stream,
                       xg4, qw, sw, h0, c0, hs);
    hipLaunchKernelGGL(logits_kernel, dim3(512), dim3(256), 0, stream,
                       hs, wout_bf, b_out, logits);
    hipLaunchKernelGGL(viterbi_kernel, dim3(32), dim3(64), 0, stream, logits, crf, out);
}

// Round 12
// 1331.231 us; speedup vs baseline: 2.1171x; 1.1199x over previous
//
#include <hip/hip_runtime.h>
#include <hip/hip_bf16.h>
#include <cstdint>

#define B_ 32
#define T_ 1024
#define E_ 256
#define H_ 256
#define G_ 1024
#define NTAG 14
#define LOG2E 1.4426950408889634f

typedef __bf16 bf8_t __attribute__((ext_vector_type(8)));
typedef float f4_t __attribute__((ext_vector_type(4)));
typedef int i4_t __attribute__((ext_vector_type(4)));
typedef unsigned short u16x4 __attribute__((ext_vector_type(4)));

__device__ __forceinline__ unsigned short f2bf(float f) {
    unsigned u = __builtin_bit_cast(unsigned, f);
    u = u + 0x7FFFu + ((u >> 16) & 1u);
    return (unsigned short)(u >> 16);
}
__device__ __forceinline__ float bf2f(unsigned short s) {
    unsigned u = ((unsigned)s) << 16;
    return __builtin_bit_cast(float, u);
}
// raw-rate transcendentals: v_exp_f32 / v_rcp_f32 (1 instr each)
__device__ __forceinline__ float fexp2(float x) { return __builtin_amdgcn_exp2f(x); }
__device__ __forceinline__ float frcp(float x) { return __builtin_amdgcn_rcpf(x); }
__device__ __forceinline__ float sigf(float x) {
    return frcp(1.0f + fexp2(-LOG2E * x));
}
// tanh(x) = 1 - 2/(exp(2x)+1); overflow-safe (exp2->inf => 1, ->0 => -1)
__device__ __forceinline__ float tanh2_(float x) {
    return 1.0f - 2.0f * frcp(fexp2((2.0f * LOG2E) * x) + 1.0f);
}
__device__ __forceinline__ f4_t mfma16(bf8_t a, bf8_t b, f4_t c) {
    return __builtin_amdgcn_mfma_f32_16x16x32_bf16(a, b, c, 0, 0, 0);
}

// ---------------- prep: wih->bf16, combine biases, wout pad ----------------
__global__ __launch_bounds__(256) void prep_kernel(
        const float* wih_f, const float* wih_b,
        const float* bih_f, const float* bhh_f,
        const float* bih_b, const float* bhh_b,
        const float* wout,
        unsigned short* wih_bf, float* biasc, unsigned short* wout_bf) {
    int tid = blockIdx.x * 256 + threadIdx.x;
    if (tid < 524288) {                       // 2 x 262144: [d][1024][256]
        int d = tid >> 18, off = tid & 262143;
        wih_bf[tid] = f2bf((d ? wih_b : wih_f)[off]);
        return;
    }
    int t2 = tid - 524288;
    if (t2 < 8192) {                          // wout padded [16][512]
        int n = t2 >> 9, k = t2 & 511;
        wout_bf[t2] = (n < NTAG) ? f2bf(wout[n * 512 + k]) : (unsigned short)0;
        return;
    }
    int t3 = t2 - 8192;
    if (t3 < 2048) {                          // biasc [2][1024]
        int d = t3 >> 10, g = t3 & 1023;
        biasc[t3] = d ? (bih_b[g] + bhh_b[g]) : (bih_f[g] + bhh_f[g]);
    }
}

// ---------------- whh -> int8 with per-row scale ----------------
__global__ __launch_bounds__(256) void wquant_kernel(const float* whh_f, const float* whh_b,
                                                     signed char* qw, float* sw) {
    int row = blockIdx.x * 4 + (threadIdx.x >> 6);   // 0..2047 = [d][1024]
    int l = threadIdx.x & 63;
    int d = row >> 10, rr = row & 1023;
    const float* src = (d ? whh_b : whh_f) + (size_t)rr * 256;
    float4 v = *reinterpret_cast<const float4*>(src + 4 * l);
    float am = fmaxf(fmaxf(fabsf(v.x), fabsf(v.y)), fmaxf(fabsf(v.z), fabsf(v.w)));
#pragma unroll
    for (int off = 1; off < 64; off <<= 1)
        am = fmaxf(am, __shfl_xor(am, off));
    am = fmaxf(am, 1e-20f);
    float inv = 127.f / am;
    int q0 = (int)__builtin_rintf(v.x * inv), q1 = (int)__builtin_rintf(v.y * inv);
    int q2 = (int)__builtin_rintf(v.z * inv), q3 = (int)__builtin_rintf(v.w * inv);
    unsigned u = (q0 & 255) | ((q1 & 255) << 8) | ((q2 & 255) << 16) | ((q3 & 255) << 24);
    *reinterpret_cast<unsigned*>(qw + (size_t)row * 256 + 4 * l) = u;
    if (l == 0) sw[row] = am / 127.f;
}

// ---------------- embedding gather -> bf16 ----------------
__global__ __launch_bounds__(256) void embed_kernel(const int* sent, const float* emb,
                                                    unsigned short* xbf) {
    int tid = blockIdx.x * 256 + threadIdx.x; // 32768*64 threads
    int bt = tid >> 6;
    int e0 = (tid & 63) << 2;
    int tok = sent[bt];
    float4 v = *reinterpret_cast<const float4*>(emb + (size_t)tok * E_ + e0);
    u16x4 o;
    o[0] = f2bf(v.x); o[1] = f2bf(v.y); o[2] = f2bf(v.z); o[3] = f2bf(v.w);
    *reinterpret_cast<u16x4*>(xbf + (size_t)bt * E_ + e0) = o;
}

// ---- input projection -> xg4[d*16+b2][t][m 2][1024 n]; B pinned in regs, 16-t loop ----
__global__ __launch_bounds__(256, 1) void xproj_kernel(const unsigned short* xbf,
        const unsigned short* wih_bf, const float* biasc, unsigned short* xg4) {
    int tt = blockIdx.x;                 // 0..63 (16 t each)
    int y = blockIdx.y;                  // d*8 + bh*4 + ns
    int ns = y & 3, bh = (y >> 2) & 1, d = y >> 3;
    int w = threadIdx.x >> 6, l = threadIdx.x & 63;
    int l15 = l & 15, lgp = l >> 4;
    __shared__ unsigned short sh[256][16];

    // B fragments: this wave's 64 n-cols x 256 k, resident for the whole t-loop
    int nbase = ns * 256 + w * 64;
    const unsigned short* wd = wih_bf + (size_t)d * 262144;
    bf8_t breg[4][8];
    float bias[4];
#pragma unroll
    for (int p = 0; p < 4; ++p) {
        int n = nbase + 16 * p + l15;
        bias[p] = biasc[d * G_ + n];
        const unsigned short* brow = wd + (size_t)n * E_ + 8 * lgp;
#pragma unroll
        for (int ks = 0; ks < 8; ++ks)
            breg[p][ks] = *reinterpret_cast<const bf8_t*>(brow + 32 * ks);
    }
#pragma unroll
    for (int p = 0; p < 4; ++p)
#pragma unroll
        for (int ks = 0; ks < 8; ++ks)
            asm volatile("" : "+v"(breg[p][ks]));

    const unsigned short* arow =
        xbf + ((size_t)(16 * bh + l15) * 1024 + tt * 16) * E_ + 8 * lgp;

    for (int it = 0; it < 16; ++it) {
        int t = tt * 16 + it;
        bf8_t a[8];
#pragma unroll
        for (int ks = 0; ks < 8; ++ks)
            a[ks] = *reinterpret_cast<const bf8_t*>(arow + 32 * ks);
        arow += 256;

        f4_t acc[4];
#pragma unroll
        for (int p = 0; p < 4; ++p) { acc[p][0] = 0.f; acc[p][1] = 0.f; acc[p][2] = 0.f; acc[p][3] = 0.f; }
#pragma unroll
        for (int p = 0; p < 4; ++p)
#pragma unroll
            for (int ks = 0; ks < 8; ++ks)
                acc[p] = mfma16(a[ks], breg[p][ks], acc[p]);

#pragma unroll
        for (int p = 0; p < 4; ++p)
#pragma unroll
            for (int r = 0; r < 4; ++r)
                sh[w * 64 + 16 * p + l15][4 * lgp + r] = f2bf(acc[p][r] + bias[p]);
        __syncthreads();
        // writeout: thread q owns n = ns*256+q; coalesced 2B stores
        int q = threadIdx.x;
#pragma unroll
        for (int p = 0; p < 8; ++p) {
            int b2g = 8 * bh + p;
            size_t base = ((size_t)(d * 16 + b2g) * 1024 + t) * 2048 + ns * 256 + q;
            xg4[base]        = sh[q][2 * p];      // m=0
            xg4[base + 1024] = sh[q][2 * p + 1];  // m=1
        }
        __syncthreads();   // protect sh reuse next iteration
    }
}

// ------- recurrence: 32 WGs = (dir, batch-pair); ALL weights in regs, 1 barrier/step ----
// A rows duplicate h (row r = batch m=r&1) => every lane's acc elems {0,1} hold
// cells (m=0,1) at its col. Lane (lgp,l15) owns cell (jt=lgp&1, m=lgp>>1).
__global__ __launch_bounds__(512, 2) void lstm_kernel(const unsigned short* xg4,
        const signed char* qw, const float* sw, const float* h0, const float* c0,
        unsigned short* hs) {
    int bid = blockIdx.x;            // 0..31
    int b2 = bid & 15, d = bid >> 4;
    int tid = threadIdx.x;
    int w = tid >> 6, l = tid & 63, l15 = l & 15, lgp = l >> 4;

    __shared__ __attribute__((aligned(16))) signed char h8[2][2][320]; // parity x m x col
    __shared__ float red_sh[8];

    const signed char* qwd = qw + (size_t)d * 262144;

    // ALL weights -> registers: 32 quads = 128 regs/lane, pinned
    i4_t wreg[4][2][4];
#pragma unroll
    for (int gt = 0; gt < 4; ++gt)
#pragma unroll
        for (int jt = 0; jt < 2; ++jt) {
            int n = 256 * gt + 32 * w + 16 * jt + l15;
#pragma unroll
            for (int ks = 0; ks < 4; ++ks)
                wreg[gt][jt][ks] = *reinterpret_cast<const i4_t*>(
                    qwd + (size_t)n * 256 + 64 * ks + 16 * lgp);
        }
#pragma unroll
    for (int gt = 0; gt < 4; ++gt)
#pragma unroll
        for (int jt = 0; jt < 2; ++jt)
#pragma unroll
            for (int ks = 0; ks < 4; ++ks)
                asm volatile("" : "+v"(wreg[gt][jt][ks]));   // keep resident

    // ---- this lane's cell ----
    int jt_c = lgp & 1, m_c = lgp >> 1;
    int j = 32 * w + 16 * jt_c + l15;

    float swv[4];
#pragma unroll
    for (int gt = 0; gt < 4; ++gt)
        swv[gt] = sw[d * 1024 + 256 * gt + j];
    float c = c0[((size_t)d * 32 + b2 * 2 + m_c) * 256 + j];

    // h0: block amax -> step-0 scale, quantize into parity-1 (512 lanes, 1 elem each)
    int im = tid >> 8, ij = tid & 255;
    float v0 = h0[((size_t)d * 32 + b2 * 2 + im) * 256 + ij];
    float am = fabsf(v0);
#pragma unroll
    for (int off = 1; off < 64; off <<= 1)
        am = fmaxf(am, __shfl_xor(am, off));
    if (l == 0) red_sh[w] = am;
    __syncthreads();
    float bmax = red_sh[0];
#pragma unroll
    for (int q = 1; q < 8; ++q) bmax = fmaxf(bmax, red_sh[q]);
    bmax = fmaxf(bmax, 1e-20f);
    float s0 = bmax / 127.f;
    h8[1][im][ij] = (signed char)(int)__builtin_rintf(v0 * (127.f / bmax));

    float dq[4];
#pragma unroll
    for (int gt = 0; gt < 4; ++gt) dq[gt] = swv[gt] * s0;

    // ---- streaming pointers (t monotone) ----
    int t0 = d ? 1023 : 0;
    int xinc = d ? -2048 : 2048;
    int hinc = d ? -512 : 512;
    const unsigned short* xq = xg4 + ((size_t)(d * 16 + b2) * 1024 + t0) * 2048
                               + m_c * 1024 + j;
    unsigned short* hsp = hs + ((size_t)(b2 * 2 + m_c) * 1024 + t0) * 512 + d * 256 + j;

    unsigned short xc[4], xn[4];
#pragma unroll
    for (int gt = 0; gt < 4; ++gt) xc[gt] = xq[256 * gt];

    i4_t z4 = (i4_t){0, 0, 0, 0};
    asm volatile("" : "+v"(z4));   // persistent zero C-operand

    __syncthreads();   // h(-1) ready

    for (int s = 0; s < 1024; ++s) {
        int rp = (s + 1) & 1, wp = s & 1;

        // prefetch next step's xg values
        if (s < 1023) {
            xq += xinc;
#pragma unroll
            for (int gt = 0; gt < 4; ++gt) xn[gt] = xq[256 * gt];
        }

        // A fragments (row r = batch m=r&1 -> full redundancy across lgp groups)
        i4_t a[4];
#pragma unroll
        for (int ks = 0; ks < 4; ++ks)
            a[ks] = *reinterpret_cast<const i4_t*>(&h8[rp][l15 & 1][64 * ks + 16 * lgp]);

        i4_t acc[4][2];
#pragma unroll
        for (int gt = 0; gt < 4; ++gt)
#pragma unroll
            for (int jt = 0; jt < 2; ++jt) {
                acc[gt][jt] = __builtin_amdgcn_mfma_i32_16x16x64_i8(
                    a[0], wreg[gt][jt][0], z4, 0, 0, 0);
#pragma unroll
                for (int ks = 1; ks < 4; ++ks)
                    acc[gt][jt] = __builtin_amdgcn_mfma_i32_16x16x64_i8(
                        a[ks], wreg[gt][jt][ks], acc[gt][jt], 0, 0, 0);
            }

        // in-register select of this lane's cell (12 cndmask, no cross-lane)
        int gi[4];
#pragma unroll
        for (int gt = 0; gt < 4; ++gt) {
            int e0 = jt_c ? acc[gt][1][0] : acc[gt][0][0];   // m=0 copy
            int e1 = jt_c ? acc[gt][1][1] : acc[gt][0][1];   // m=1 copy
            gi[gt] = m_c ? e1 : e0;
        }

        // epilogue: every lane computes its one cell (raw v_exp/v_rcp)
        float pi = dq[0] * (float)gi[0] + bf2f(xc[0]);
        float pf = dq[1] * (float)gi[1] + bf2f(xc[1]);
        float pg = dq[2] * (float)gi[2] + bf2f(xc[2]);
        float po = dq[3] * (float)gi[3] + bf2f(xc[3]);
        float iv = sigf(pi), fv = sigf(pf), ov = sigf(po);
        float gv = tanh2_(pg);
        float cn = fv * c + iv * gv;
        c = cn;
        float hv = ov * tanh2_(cn);
        *hsp = f2bf(hv);
        hsp += hinc;
        h8[wp][m_c][j] = (signed char)(int)__builtin_rintf(hv * 127.f);

        if (s == 0) {
#pragma unroll
            for (int gt = 0; gt < 4; ++gt) dq[gt] = swv[gt] * (1.f / 127.f);
        }
#pragma unroll
        for (int gt = 0; gt < 4; ++gt) xc[gt] = xn[gt];

        // single barrier: h8[wp] complete for next step (tiny LDS drain)
        asm volatile("s_waitcnt lgkmcnt(0)" ::: "memory");
        __builtin_amdgcn_sched_barrier(0);
        __builtin_amdgcn_s_barrier();
    }
}

// ---------------- logits = hs @ Wout^T + b_out (N padded to 16) ----------------
__global__ __launch_bounds__(256) void logits_kernel(const unsigned short* hs,
        const unsigned short* wout_bf, const float* b_out, float* logits) {
    int w = threadIdx.x >> 6, l = threadIdx.x & 63, l15 = l & 15, lgp = l >> 4;
    int mt = blockIdx.x * 4 + w;         // 0..2047
    const unsigned short* arow = hs + (size_t)(16 * mt + l15) * 512 + 8 * lgp;
    const unsigned short* brow = wout_bf + (size_t)l15 * 512 + 8 * lgp;
    f4_t acc; acc[0] = 0.f; acc[1] = 0.f; acc[2] = 0.f; acc[3] = 0.f;
#pragma unroll
    for (int ks = 0; ks < 16; ++ks) {
        bf8_t a = *reinterpret_cast<const bf8_t*>(arow + 32 * ks);
        bf8_t b = *reinterpret_cast<const bf8_t*>(brow + 32 * ks);
        acc = mfma16(a, b, acc);
    }
    float bo = (l15 < NTAG) ? b_out[l15] : 0.0f;
#pragma unroll
    for (int r = 0; r < 4; ++r) {
        int bt = 16 * mt + 4 * lgp + r;
        logits[(size_t)bt * 16 + l15] = acc[r] + bo;
    }
}

// ---------------- Viterbi: one wave per sequence; tree argmax ----------------
__global__ __launch_bounds__(64) void viterbi_kernel(const float* logits, const float* crf,
                                                     float* out) {
    int b = blockIdx.x, j = threadIdx.x;
    __shared__ unsigned char bp[1024][16];
    __shared__ unsigned char pth[1024];
    float crfj[NTAG];
#pragma unroll
    for (int i = 0; i < NTAG; ++i)
        crfj[i] = (j < NTAG) ? crf[i * NTAG + j] : 0.0f;
    const float* lgt = logits + (size_t)b * 1024 * 16;
    float v = (j < NTAG) ? lgt[j] : -3.0e38f;
    float lt_nxt = (j < NTAG) ? lgt[16 + j] : 0.0f;
    for (int t = 1; t < 1024; ++t) {
        float lt = lt_nxt;
        if (t < 1023) lt_nxt = (j < NTAG) ? lgt[(t + 1) * 16 + j] : 0.0f;
        float sv[NTAG];
#pragma unroll
        for (int i = 0; i < NTAG; ++i)
            sv[i] = __shfl(v, i) + crfj[i];
        // tree argmax (lowest index wins on ties: right only if strictly >)
        float av[7]; int ai[7];
#pragma unroll
        for (int i = 0; i < 7; ++i) {
            bool rgt = sv[2 * i + 1] > sv[2 * i];
            av[i] = rgt ? sv[2 * i + 1] : sv[2 * i];
            ai[i] = rgt ? 2 * i + 1 : 2 * i;
        }
        float bv[4]; int bi[4];
#pragma unroll
        for (int i = 0; i < 3; ++i) {
            bool rgt = av[2 * i + 1] > av[2 * i];
            bv[i] = rgt ? av[2 * i + 1] : av[2 * i];
            bi[i] = rgt ? ai[2 * i + 1] : ai[2 * i];
        }
        bv[3] = av[6]; bi[3] = ai[6];
        float cv0 = (bv[1] > bv[0]) ? bv[1] : bv[0];
        int   ci0 = (bv[1] > bv[0]) ? bi[1] : bi[0];
        float cv1 = (bv[3] > bv[2]) ? bv[3] : bv[2];
        int   ci1 = (bv[3] > bv[2]) ? bi[3] : bi[2];
        float best = (cv1 > cv0) ? cv1 : cv0;
        int   arg  = (cv1 > cv0) ? ci1 : ci0;
        v = (j < NTAG) ? (lt + best) : -3.0e38f;
        if (j < 16) bp[t][j] = (unsigned char)arg;
    }
    float best = -3.0e38f; int tag = 0;
#pragma unroll
    for (int jj = 0; jj < NTAG; ++jj) {
        float s = __shfl(v, jj);
        if (s > best) { best = s; tag = jj; }
    }
    __syncthreads();
    if (j == 0) {
        out[b] = best;
        int tg = tag;
        pth[1023] = (unsigned char)tg;
        for (int t = 1023; t >= 1; --t) {
            tg = bp[t][tg];
            pth[t - 1] = (unsigned char)tg;
        }
    }
    __syncthreads();
    float* pout = out + 32 + (size_t)b * 1024;
    for (int t = j; t < 1024; t += 64)
        pout[t] = (float)pth[t];
}

extern "C" void kernel_launch(void* const* d_in, const int* in_sizes, int n_in,
                              void* d_out, int out_size, void* d_ws, size_t ws_size,
                              hipStream_t stream) {
    const int* sent = (const int*)d_in[0];
    const float* emb = (const float*)d_in[1];
    const float* wih_f = (const float*)d_in[2];
    const float* whh_f = (const float*)d_in[3];
    const float* bih_f = (const float*)d_in[4];
    const float* bhh_f = (const float*)d_in[5];
    const float* wih_b = (const float*)d_in[6];
    const float* whh_b = (const float*)d_in[7];
    const float* bih_b = (const float*)d_in[8];
    const float* bhh_b = (const float*)d_in[9];
    const float* h0 = (const float*)d_in[10];
    const float* c0 = (const float*)d_in[11];
    const float* wout = (const float*)d_in[12];
    const float* b_out = (const float*)d_in[13];
    const float* crf = (const float*)d_in[14];

    char* ws = (char*)d_ws;
    signed char* qw       = (signed char*)(ws + 0);               // 512 KiB
    float* sw             = (float*)(ws + 524288);                // 8 KiB
    unsigned short* wih_bf = (unsigned short*)(ws + 1048576);     // 1 MiB
    float* biasc          = (float*)(ws + 2097152);               // 8 KiB
    unsigned short* wout_bf = (unsigned short*)(ws + 2105344);    // 16 KiB
    unsigned short* xbf   = (unsigned short*)(ws + 2121728);      // 16 MiB
    unsigned short* xg4   = (unsigned short*)(ws + 18898944);     // 128 MiB
    unsigned short* hs    = (unsigned short*)(ws + 153116672);    // 32 MiB
    float* logits         = (float*)(ws + 186671104);             // 2 MiB
    float* out = (float*)d_out;

    hipLaunchKernelGGL(prep_kernel, dim3(2088), dim3(256), 0, stream,
                       wih_f, wih_b, bih_f, bhh_f, bih_b, bhh_b, wout,
                       wih_bf, biasc, wout_bf);
    hipLaunchKernelGGL(wquant_kernel, dim3(512), dim3(256), 0, stream,
                       whh_f, whh_b, qw, sw);
    hipLaunchKernelGGL(embed_kernel, dim3(8192), dim3(256), 0, stream, sent, emb, xbf);
    hipLaunchKernelGGL(xproj_kernel, dim3(64, 16), dim3(256), 0, stream,
                       xbf, wih_bf, biasc, xg4);
    hipLaunchKernelGGL(lstm_kernel, dim3(32), dim3(512), 0, stream,
                       xg4, qw, sw, h0, c0, hs);
    hipLaunchKernelGGL(logits_kernel, dim3(512), dim3(256), 0, stream,
                       hs, wout_bf, b_out, logits);
    hipLaunchKernelGGL(viterbi_kernel, dim3(32), dim3(64), 0, stream, logits, crf, out);
}

// Round 14
// 1325.893 us; speedup vs baseline: 2.1257x; 1.0040x over previous
//
#include <hip/hip_runtime.h>
#include <hip/hip_bf16.h>
#include <cstdint>

#define B_ 32
#define T_ 1024
#define E_ 256
#define H_ 256
#define G_ 1024
#define NTAG 14
#define LOG2E 1.4426950408889634f

typedef __bf16 bf8_t __attribute__((ext_vector_type(8)));
typedef float f4_t __attribute__((ext_vector_type(4)));
typedef int i4_t __attribute__((ext_vector_type(4)));
typedef unsigned short u16x4 __attribute__((ext_vector_type(4)));

__device__ __forceinline__ unsigned short f2bf(float f) {
    unsigned u = __builtin_bit_cast(unsigned, f);
    u = u + 0x7FFFu + ((u >> 16) & 1u);
    return (unsigned short)(u >> 16);
}
__device__ __forceinline__ float bf2f(unsigned short s) {
    unsigned u = ((unsigned)s) << 16;
    return __builtin_bit_cast(float, u);
}
__device__ __forceinline__ float fexp2(float x) { return __builtin_amdgcn_exp2f(x); }
__device__ __forceinline__ float frcp(float x) { return __builtin_amdgcn_rcpf(x); }
__device__ __forceinline__ float sigf(float x) {
    return frcp(1.0f + fexp2(-LOG2E * x));
}
__device__ __forceinline__ float tanh2_(float x) {
    return 1.0f - 2.0f * frcp(fexp2((2.0f * LOG2E) * x) + 1.0f);
}
__device__ __forceinline__ f4_t mfma16(bf8_t a, bf8_t b, f4_t c) {
    return __builtin_amdgcn_mfma_f32_16x16x32_bf16(a, b, c, 0, 0, 0);
}

// ------- setup: embed gather + whh int8 quant + wih bf16 + biases + wout pad ----
// Pure data-parallel, no inter-WG dependencies of any kind.
__global__ __launch_bounds__(256) void setup_kernel(
        const int* sent, const float* emb,
        const float* whh_f, const float* whh_b,
        const float* wih_f, const float* wih_b,
        const float* bih_f, const float* bhh_f,
        const float* bih_b, const float* bhh_b,
        const float* wout,
        unsigned short* xbf, signed char* qw, float* sw,
        unsigned short* wih_bf, float* biasc, unsigned short* wout_bf) {
    int bid = blockIdx.x, thr = threadIdx.x;
    if (bid < 8192) {                         // embed: 32768 rows x 64 lanes
        int tid = bid * 256 + thr;
        int bt = tid >> 6;
        int e0 = (tid & 63) << 2;
        int tok = sent[bt];
        float4 v = *reinterpret_cast<const float4*>(emb + (size_t)tok * E_ + e0);
        u16x4 o;
        o[0] = f2bf(v.x); o[1] = f2bf(v.y); o[2] = f2bf(v.z); o[3] = f2bf(v.w);
        *reinterpret_cast<u16x4*>(xbf + (size_t)bt * E_ + e0) = o;
        return;
    }
    if (bid < 8704) {                         // wquant: rows [d][1024], per-row scale
        int row = (bid - 8192) * 4 + (thr >> 6);
        int l = thr & 63;
        int d = row >> 10, rr = row & 1023;
        const float* src = (d ? whh_b : whh_f) + (size_t)rr * 256;
        float4 v = *reinterpret_cast<const float4*>(src + 4 * l);
        float am = fmaxf(fmaxf(fabsf(v.x), fabsf(v.y)), fmaxf(fabsf(v.z), fabsf(v.w)));
#pragma unroll
        for (int off = 1; off < 64; off <<= 1)
            am = fmaxf(am, __shfl_xor(am, off));
        am = fmaxf(am, 1e-20f);
        float inv = 127.f / am;
        int q0 = (int)__builtin_rintf(v.x * inv), q1 = (int)__builtin_rintf(v.y * inv);
        int q2 = (int)__builtin_rintf(v.z * inv), q3 = (int)__builtin_rintf(v.w * inv);
        unsigned u = (q0 & 255) | ((q1 & 255) << 8) | ((q2 & 255) << 16) | ((q3 & 255) << 24);
        *reinterpret_cast<unsigned*>(qw + (size_t)row * 256 + 4 * l) = u;
        if (l == 0) sw[row] = am / 127.f;
        return;
    }
    int tid = (bid - 8704) * 256 + thr;       // prep: 534528 work items
    if (tid < 524288) {
        int d = tid >> 18, off = tid & 262143;
        wih_bf[tid] = f2bf((d ? wih_b : wih_f)[off]);
        return;
    }
    int t2 = tid - 524288;
    if (t2 < 8192) {
        int n = t2 >> 9, k = t2 & 511;
        wout_bf[t2] = (n < NTAG) ? f2bf(wout[n * 512 + k]) : (unsigned short)0;
        return;
    }
    int t3 = t2 - 8192;
    if (t3 < 2048) {
        int d = t3 >> 10, g = t3 & 1023;
        biasc[t3] = d ? (bih_b[g] + bhh_b[g]) : (bih_f[g] + bhh_f[g]);
    }
}

// ---- input projection -> xg4[d*16+b2][t][m 2][1024 n]; B pinned in regs, 16-t loop ----
__global__ __launch_bounds__(256, 1) void xproj_kernel(const unsigned short* xbf,
        const unsigned short* wih_bf, const float* biasc, unsigned short* xg4) {
    int tt = blockIdx.x;                 // 0..63 (16 t each)
    int y = blockIdx.y;                  // d*8 + bh*4 + ns
    int ns = y & 3, bh = (y >> 2) & 1, d = y >> 3;
    int w = threadIdx.x >> 6, l = threadIdx.x & 63;
    int l15 = l & 15, lgp = l >> 4;
    __shared__ unsigned short sh[256][16];

    // B fragments: this wave's 64 n-cols x 256 k, resident for the whole t-loop
    int nbase = ns * 256 + w * 64;
    const unsigned short* wd = wih_bf + (size_t)d * 262144;
    bf8_t breg[4][8];
    float bias[4];
#pragma unroll
    for (int p = 0; p < 4; ++p) {
        int n = nbase + 16 * p + l15;
        bias[p] = biasc[d * G_ + n];
        const unsigned short* brow = wd + (size_t)n * E_ + 8 * lgp;
#pragma unroll
        for (int ks = 0; ks < 8; ++ks)
            breg[p][ks] = *reinterpret_cast<const bf8_t*>(brow + 32 * ks);
    }
#pragma unroll
    for (int p = 0; p < 4; ++p)
#pragma unroll
        for (int ks = 0; ks < 8; ++ks)
            asm volatile("" : "+v"(breg[p][ks]));

    const unsigned short* arow =
        xbf + ((size_t)(16 * bh + l15) * 1024 + tt * 16) * E_ + 8 * lgp;

    for (int it = 0; it < 16; ++it) {
        int t = tt * 16 + it;
        bf8_t a[8];
#pragma unroll
        for (int ks = 0; ks < 8; ++ks)
            a[ks] = *reinterpret_cast<const bf8_t*>(arow + 32 * ks);
        arow += 256;

        f4_t acc[4];
#pragma unroll
        for (int p = 0; p < 4; ++p) { acc[p][0] = 0.f; acc[p][1] = 0.f; acc[p][2] = 0.f; acc[p][3] = 0.f; }
#pragma unroll
        for (int p = 0; p < 4; ++p)
#pragma unroll
            for (int ks = 0; ks < 8; ++ks)
                acc[p] = mfma16(a[ks], breg[p][ks], acc[p]);

#pragma unroll
        for (int p = 0; p < 4; ++p)
#pragma unroll
            for (int r = 0; r < 4; ++r)
                sh[w * 64 + 16 * p + l15][4 * lgp + r] = f2bf(acc[p][r] + bias[p]);
        __syncthreads();
        // writeout: thread q owns n = ns*256+q; coalesced 2B stores
        int q = threadIdx.x;
#pragma unroll
        for (int p = 0; p < 8; ++p) {
            int b2g = 8 * bh + p;
            size_t base = ((size_t)(d * 16 + b2g) * 1024 + t) * 2048 + ns * 256 + q;
            xg4[base]        = sh[q][2 * p];      // m=0
            xg4[base + 1024] = sh[q][2 * p + 1];  // m=1
        }
        __syncthreads();   // protect sh reuse next iteration
    }
}

// ------- recurrence: 32 WGs = (dir, batch-pair); ALL weights in regs, 1 barrier/step ----
// A rows duplicate h (row r = batch m=r&1) => every lane's acc elems {0,1} hold
// cells (m=0,1) at its col. Lane (lgp,l15) owns cell (jt=lgp&1, m=lgp>>1).
__global__ __launch_bounds__(512, 2) void lstm_kernel(const unsigned short* xg4,
        const signed char* qw, const float* sw, const float* h0, const float* c0,
        unsigned short* hs) {
    int bid = blockIdx.x;            // 0..31
    int b2 = bid & 15, d = bid >> 4;
    int tid = threadIdx.x;
    int w = tid >> 6, l = tid & 63, l15 = l & 15, lgp = l >> 4;

    __shared__ __attribute__((aligned(16))) signed char h8[2][2][320]; // parity x m x col
    __shared__ float red_sh[8];

    const signed char* qwd = qw + (size_t)d * 262144;

    // ALL weights -> registers: 32 quads = 128 regs/lane, pinned
    i4_t wreg[4][2][4];
#pragma unroll
    for (int gt = 0; gt < 4; ++gt)
#pragma unroll
        for (int jt = 0; jt < 2; ++jt) {
            int n = 256 * gt + 32 * w + 16 * jt + l15;
#pragma unroll
            for (int ks = 0; ks < 4; ++ks)
                wreg[gt][jt][ks] = *reinterpret_cast<const i4_t*>(
                    qwd + (size_t)n * 256 + 64 * ks + 16 * lgp);
        }
#pragma unroll
    for (int gt = 0; gt < 4; ++gt)
#pragma unroll
        for (int jt = 0; jt < 2; ++jt)
#pragma unroll
            for (int ks = 0; ks < 4; ++ks)
                asm volatile("" : "+v"(wreg[gt][jt][ks]));   // keep resident

    // ---- this lane's cell ----
    int jt_c = lgp & 1, m_c = lgp >> 1;
    int j = 32 * w + 16 * jt_c + l15;

    float swv[4];
#pragma unroll
    for (int gt = 0; gt < 4; ++gt)
        swv[gt] = sw[d * 1024 + 256 * gt + j];
    float c = c0[((size_t)d * 32 + b2 * 2 + m_c) * 256 + j];

    // h0: block amax -> step-0 scale, quantize into parity-1 (512 lanes, 1 elem each)
    int im = tid >> 8, ij = tid & 255;
    float v0 = h0[((size_t)d * 32 + b2 * 2 + im) * 256 + ij];
    float am = fabsf(v0);
#pragma unroll
    for (int off = 1; off < 64; off <<= 1)
        am = fmaxf(am, __shfl_xor(am, off));
    if (l == 0) red_sh[w] = am;
    __syncthreads();
    float bmax = red_sh[0];
#pragma unroll
    for (int q = 1; q < 8; ++q) bmax = fmaxf(bmax, red_sh[q]);
    bmax = fmaxf(bmax, 1e-20f);
    float s0 = bmax / 127.f;
    h8[1][im][ij] = (signed char)(int)__builtin_rintf(v0 * (127.f / bmax));

    float dq[4];
#pragma unroll
    for (int gt = 0; gt < 4; ++gt) dq[gt] = swv[gt] * s0;

    // ---- streaming pointers (t monotone) ----
    int t0 = d ? 1023 : 0;
    int xinc = d ? -2048 : 2048;
    int hinc = d ? -512 : 512;
    const unsigned short* xq = xg4 + ((size_t)(d * 16 + b2) * 1024 + t0) * 2048
                               + m_c * 1024 + j;
    unsigned short* hsp = hs + ((size_t)(b2 * 2 + m_c) * 1024 + t0) * 512 + d * 256 + j;

    unsigned short xc[4], xn[4];
#pragma unroll
    for (int gt = 0; gt < 4; ++gt) xc[gt] = xq[256 * gt];

    i4_t z4 = (i4_t){0, 0, 0, 0};
    asm volatile("" : "+v"(z4));   // persistent zero C-operand

    __syncthreads();   // h(-1) ready

    for (int s = 0; s < 1024; ++s) {
        int rp = (s + 1) & 1, wp = s & 1;

        // prefetch next step's xg values
        if (s < 1023) {
            xq += xinc;
#pragma unroll
            for (int gt = 0; gt < 4; ++gt) xn[gt] = xq[256 * gt];
        }

        // A fragments (row r = batch m=r&1 -> full redundancy across lgp groups)
        i4_t a[4];
#pragma unroll
        for (int ks = 0; ks < 4; ++ks)
            a[ks] = *reinterpret_cast<const i4_t*>(&h8[rp][l15 & 1][64 * ks + 16 * lgp]);

        i4_t acc[4][2];
#pragma unroll
        for (int gt = 0; gt < 4; ++gt)
#pragma unroll
            for (int jt = 0; jt < 2; ++jt) {
                acc[gt][jt] = __builtin_amdgcn_mfma_i32_16x16x64_i8(
                    a[0], wreg[gt][jt][0], z4, 0, 0, 0);
#pragma unroll
                for (int ks = 1; ks < 4; ++ks)
                    acc[gt][jt] = __builtin_amdgcn_mfma_i32_16x16x64_i8(
                        a[ks], wreg[gt][jt][ks], acc[gt][jt], 0, 0, 0);
            }

        // in-register select of this lane's cell (12 cndmask, no cross-lane)
        int gi[4];
#pragma unroll
        for (int gt = 0; gt < 4; ++gt) {
            int e0 = jt_c ? acc[gt][1][0] : acc[gt][0][0];   // m=0 copy
            int e1 = jt_c ? acc[gt][1][1] : acc[gt][0][1];   // m=1 copy
            gi[gt] = m_c ? e1 : e0;
        }

        // epilogue: every lane computes its one cell (raw v_exp/v_rcp)
        float pi = dq[0] * (float)gi[0] + bf2f(xc[0]);
        float pf = dq[1] * (float)gi[1] + bf2f(xc[1]);
        float pg = dq[2] * (float)gi[2] + bf2f(xc[2]);
        float po = dq[3] * (float)gi[3] + bf2f(xc[3]);
        float iv = sigf(pi), fv = sigf(pf), ov = sigf(po);
        float gv = tanh2_(pg);
        float cn = fv * c + iv * gv;
        c = cn;
        float hv = ov * tanh2_(cn);
        *hsp = f2bf(hv);
        hsp += hinc;
        h8[wp][m_c][j] = (signed char)(int)__builtin_rintf(hv * 127.f);

        if (s == 0) {
#pragma unroll
            for (int gt = 0; gt < 4; ++gt) dq[gt] = swv[gt] * (1.f / 127.f);
        }
#pragma unroll
        for (int gt = 0; gt < 4; ++gt) xc[gt] = xn[gt];

        // single barrier: h8[wp] complete for next step (tiny LDS drain)
        asm volatile("s_waitcnt lgkmcnt(0)" ::: "memory");
        __builtin_amdgcn_sched_barrier(0);
        __builtin_amdgcn_s_barrier();
    }
}

// ---------------- logits = hs @ Wout^T + b_out (N padded to 16) ----------------
__global__ __launch_bounds__(256) void logits_kernel(const unsigned short* hs,
        const unsigned short* wout_bf, const float* b_out, float* logits) {
    int w = threadIdx.x >> 6, l = threadIdx.x & 63, l15 = l & 15, lgp = l >> 4;
    int mt = blockIdx.x * 4 + w;         // 0..2047
    const unsigned short* arow = hs + (size_t)(16 * mt + l15) * 512 + 8 * lgp;
    const unsigned short* brow = wout_bf + (size_t)l15 * 512 + 8 * lgp;
    f4_t acc; acc[0] = 0.f; acc[1] = 0.f; acc[2] = 0.f; acc[3] = 0.f;
#pragma unroll
    for (int ks = 0; ks < 16; ++ks) {
        bf8_t a = *reinterpret_cast<const bf8_t*>(arow + 32 * ks);
        bf8_t b = *reinterpret_cast<const bf8_t*>(brow + 32 * ks);
        acc = mfma16(a, b, acc);
    }
    float bo = (l15 < NTAG) ? b_out[l15] : 0.0f;
#pragma unroll
    for (int r = 0; r < 4; ++r) {
        int bt = 16 * mt + 4 * lgp + r;
        logits[(size_t)bt * 16 + l15] = acc[r] + bo;
    }
}

// ---------------- Viterbi: one wave per sequence; tree argmax ----------------
__global__ __launch_bounds__(64) void viterbi_kernel(const float* logits, const float* crf,
                                                     float* out) {
    int b = blockIdx.x, j = threadIdx.x;
    __shared__ unsigned char bp[1024][16];
    __shared__ unsigned char pth[1024];
    float crfj[NTAG];
#pragma unroll
    for (int i = 0; i < NTAG; ++i)
        crfj[i] = (j < NTAG) ? crf[i * NTAG + j] : 0.0f;
    const float* lgt = logits + (size_t)b * 1024 * 16;
    float v = (j < NTAG) ? lgt[j] : -3.0e38f;
    float lt_nxt = (j < NTAG) ? lgt[16 + j] : 0.0f;
    for (int t = 1; t < 1024; ++t) {
        float lt = lt_nxt;
        if (t < 1023) lt_nxt = (j < NTAG) ? lgt[(t + 1) * 16 + j] : 0.0f;
        float sv[NTAG];
#pragma unroll
        for (int i = 0; i < NTAG; ++i)
            sv[i] = __shfl(v, i) + crfj[i];
        // tree argmax (lowest index wins on ties: right only if strictly >)
        float av[7]; int ai[7];
#pragma unroll
        for (int i = 0; i < 7; ++i) {
            bool rgt = sv[2 * i + 1] > sv[2 * i];
            av[i] = rgt ? sv[2 * i + 1] : sv[2 * i];
            ai[i] = rgt ? 2 * i + 1 : 2 * i;
        }
        float bv[4]; int bi[4];
#pragma unroll
        for (int i = 0; i < 3; ++i) {
            bool rgt = av[2 * i + 1] > av[2 * i];
            bv[i] = rgt ? av[2 * i + 1] : av[2 * i];
            bi[i] = rgt ? ai[2 * i + 1] : ai[2 * i];
        }
        bv[3] = av[6]; bi[3] = ai[6];
        float cv0 = (bv[1] > bv[0]) ? bv[1] : bv[0];
        int   ci0 = (bv[1] > bv[0]) ? bi[1] : bi[0];
        float cv1 = (bv[3] > bv[2]) ? bv[3] : bv[2];
        int   ci1 = (bv[3] > bv[2]) ? bi[3] : bi[2];
        float best = (cv1 > cv0) ? cv1 : cv0;
        int   arg  = (cv1 > cv0) ? ci1 : ci0;
        v = (j < NTAG) ? (lt + best) : -3.0e38f;
        if (j < 16) bp[t][j] = (unsigned char)arg;
    }
    float best = -3.0e38f; int tag = 0;
#pragma unroll
    for (int jj = 0; jj < NTAG; ++jj) {
        float s = __shfl(v, jj);
        if (s > best) { best = s; tag = jj; }
    }
    __syncthreads();
    if (j == 0) {
        out[b] = best;
        int tg = tag;
        pth[1023] = (unsigned char)tg;
        for (int t = 1023; t >= 1; --t) {
            tg = bp[t][tg];
            pth[t - 1] = (unsigned char)tg;
        }
    }
    __syncthreads();
    float* pout = out + 32 + (size_t)b * 1024;
    for (int t = j; t < 1024; t += 64)
        pout[t] = (float)pth[t];
}

extern "C" void kernel_launch(void* const* d_in, const int* in_sizes, int n_in,
                              void* d_out, int out_size, void* d_ws, size_t ws_size,
                              hipStream_t stream) {
    const int* sent = (const int*)d_in[0];
    const float* emb = (const float*)d_in[1];
    const float* wih_f = (const float*)d_in[2];
    const float* whh_f = (const float*)d_in[3];
    const float* bih_f = (const float*)d_in[4];
    const float* bhh_f = (const float*)d_in[5];
    const float* wih_b = (const float*)d_in[6];
    const float* whh_b = (const float*)d_in[7];
    const float* bih_b = (const float*)d_in[8];
    const float* bhh_b = (const float*)d_in[9];
    const float* h0 = (const float*)d_in[10];
    const float* c0 = (const float*)d_in[11];
    const float* wout = (const float*)d_in[12];
    const float* b_out = (const float*)d_in[13];
    const float* crf = (const float*)d_in[14];

    char* ws = (char*)d_ws;
    signed char* qw       = (signed char*)(ws + 0);               // 512 KiB
    float* sw             = (float*)(ws + 524288);                // 8 KiB
    unsigned short* wih_bf = (unsigned short*)(ws + 1048576);     // 1 MiB
    float* biasc          = (float*)(ws + 2097152);               // 8 KiB
    unsigned short* wout_bf = (unsigned short*)(ws + 2105344);    // 16 KiB
    unsigned short* xbf   = (unsigned short*)(ws + 2121728);      // 16 MiB
    unsigned short* xg4   = (unsigned short*)(ws + 18898944);     // 128 MiB
    unsigned short* hs    = (unsigned short*)(ws + 153116672);    // 32 MiB
    float* logits         = (float*)(ws + 186671104);             // 2 MiB
    float* out = (float*)d_out;

    hipLaunchKernelGGL(setup_kernel, dim3(10792), dim3(256), 0, stream,
                       sent, emb, whh_f, whh_b, wih_f, wih_b,
                       bih_f, bhh_f, bih_b, bhh_b, wout,
                       xbf, qw, sw, wih_bf, biasc, wout_bf);
    hipLaunchKernelGGL(xproj_kernel, dim3(64, 16), dim3(256), 0, stream,
                       xbf, wih_bf, biasc, xg4);
    hipLaunchKernelGGL(lstm_kernel, dim3(32), dim3(512), 0, stream,
                       xg4, qw, sw, h0, c0, hs);
    hipLaunchKernelGGL(logits_kernel, dim3(512), dim3(256), 0, stream,
                       hs, wout_bf, b_out, logits);
    hipLaunchKernelGGL(viterbi_kernel, dim3(32), dim3(64), 0, stream, logits, crf, out);
}

// Round 15
// 1168.040 us; speedup vs baseline: 2.4129x; 1.1351x over previous
//
#include <hip/hip_runtime.h>
#include <hip/hip_bf16.h>
#include <cstdint>

#define B_ 32
#define T_ 1024
#define E_ 256
#define H_ 256
#define G_ 1024
#define NTAG 14
#define LOG2E 1.4426950408889634f

typedef __bf16 bf8_t __attribute__((ext_vector_type(8)));
typedef float f4_t __attribute__((ext_vector_type(4)));
typedef int i4_t __attribute__((ext_vector_type(4)));
typedef unsigned short u16x4 __attribute__((ext_vector_type(4)));

__device__ __forceinline__ unsigned short f2bf(float f) {
    unsigned u = __builtin_bit_cast(unsigned, f);
    u = u + 0x7FFFu + ((u >> 16) & 1u);
    return (unsigned short)(u >> 16);
}
__device__ __forceinline__ float bf2f(unsigned short s) {
    unsigned u = ((unsigned)s) << 16;
    return __builtin_bit_cast(float, u);
}
__device__ __forceinline__ float fexp2(float x) { return __builtin_amdgcn_exp2f(x); }
__device__ __forceinline__ float frcp(float x) { return __builtin_amdgcn_rcpf(x); }
__device__ __forceinline__ float sigf(float x) {
    return frcp(1.0f + fexp2(-LOG2E * x));
}
__device__ __forceinline__ float tanh2_(float x) {
    return 1.0f - 2.0f * frcp(fexp2((2.0f * LOG2E) * x) + 1.0f);
}
__device__ __forceinline__ f4_t mfma16(bf8_t a, bf8_t b, f4_t c) {
    return __builtin_amdgcn_mfma_f32_16x16x32_bf16(a, b, c, 0, 0, 0);
}

// ------- setup: embed gather + whh int8 quant + wih bf16 + biases + wout pad ----
__global__ __launch_bounds__(256) void setup_kernel(
        const int* sent, const float* emb,
        const float* whh_f, const float* whh_b,
        const float* wih_f, const float* wih_b,
        const float* bih_f, const float* bhh_f,
        const float* bih_b, const float* bhh_b,
        const float* wout,
        unsigned short* xbf, signed char* qw, float* sw,
        unsigned short* wih_bf, float* biasc, unsigned short* wout_bf) {
    int bid = blockIdx.x, thr = threadIdx.x;
    if (bid < 8192) {                         // embed: 32768 rows x 64 lanes
        int tid = bid * 256 + thr;
        int bt = tid >> 6;
        int e0 = (tid & 63) << 2;
        int tok = sent[bt];
        float4 v = *reinterpret_cast<const float4*>(emb + (size_t)tok * E_ + e0);
        u16x4 o;
        o[0] = f2bf(v.x); o[1] = f2bf(v.y); o[2] = f2bf(v.z); o[3] = f2bf(v.w);
        *reinterpret_cast<u16x4*>(xbf + (size_t)bt * E_ + e0) = o;
        return;
    }
    if (bid < 8704) {                         // wquant: rows [d][1024], per-row scale
        int row = (bid - 8192) * 4 + (thr >> 6);
        int l = thr & 63;
        int d = row >> 10, rr = row & 1023;
        const float* src = (d ? whh_b : whh_f) + (size_t)rr * 256;
        float4 v = *reinterpret_cast<const float4*>(src + 4 * l);
        float am = fmaxf(fmaxf(fabsf(v.x), fabsf(v.y)), fmaxf(fabsf(v.z), fabsf(v.w)));
#pragma unroll
        for (int off = 1; off < 64; off <<= 1)
            am = fmaxf(am, __shfl_xor(am, off));
        am = fmaxf(am, 1e-20f);
        float inv = 127.f / am;
        int q0 = (int)__builtin_rintf(v.x * inv), q1 = (int)__builtin_rintf(v.y * inv);
        int q2 = (int)__builtin_rintf(v.z * inv), q3 = (int)__builtin_rintf(v.w * inv);
        unsigned u = (q0 & 255) | ((q1 & 255) << 8) | ((q2 & 255) << 16) | ((q3 & 255) << 24);
        *reinterpret_cast<unsigned*>(qw + (size_t)row * 256 + 4 * l) = u;
        if (l == 0) sw[row] = am / 127.f;
        return;
    }
    int tid = (bid - 8704) * 256 + thr;       // prep: 534528 work items
    if (tid < 524288) {
        int d = tid >> 18, off = tid & 262143;
        wih_bf[tid] = f2bf((d ? wih_b : wih_f)[off]);
        return;
    }
    int t2 = tid - 524288;
    if (t2 < 8192) {
        int n = t2 >> 9, k = t2 & 511;
        wout_bf[t2] = (n < NTAG) ? f2bf(wout[n * 512 + k]) : (unsigned short)0;
        return;
    }
    int t3 = t2 - 8192;
    if (t3 < 2048) {
        int d = t3 >> 10, g = t3 & 1023;
        biasc[t3] = d ? (bih_b[g] + bhh_b[g]) : (bih_f[g] + bhh_f[g]);
    }
}

// ---- input projection -> xg4[d*16+b2][t][m 2][1024 n]; B pinned in regs, 16-t loop ----
__global__ __launch_bounds__(256, 1) void xproj_kernel(const unsigned short* xbf,
        const unsigned short* wih_bf, const float* biasc, unsigned short* xg4) {
    int tt = blockIdx.x;                 // 0..63 (16 t each)
    int y = blockIdx.y;                  // d*8 + bh*4 + ns
    int ns = y & 3, bh = (y >> 2) & 1, d = y >> 3;
    int w = threadIdx.x >> 6, l = threadIdx.x & 63;
    int l15 = l & 15, lgp = l >> 4;
    __shared__ unsigned short sh[256][16];

    int nbase = ns * 256 + w * 64;
    const unsigned short* wd = wih_bf + (size_t)d * 262144;
    bf8_t breg[4][8];
    float bias[4];
#pragma unroll
    for (int p = 0; p < 4; ++p) {
        int n = nbase + 16 * p + l15;
        bias[p] = biasc[d * G_ + n];
        const unsigned short* brow = wd + (size_t)n * E_ + 8 * lgp;
#pragma unroll
        for (int ks = 0; ks < 8; ++ks)
            breg[p][ks] = *reinterpret_cast<const bf8_t*>(brow + 32 * ks);
    }
#pragma unroll
    for (int p = 0; p < 4; ++p)
#pragma unroll
        for (int ks = 0; ks < 8; ++ks)
            asm volatile("" : "+v"(breg[p][ks]));

    const unsigned short* arow =
        xbf + ((size_t)(16 * bh + l15) * 1024 + tt * 16) * E_ + 8 * lgp;

    for (int it = 0; it < 16; ++it) {
        int t = tt * 16 + it;
        bf8_t a[8];
#pragma unroll
        for (int ks = 0; ks < 8; ++ks)
            a[ks] = *reinterpret_cast<const bf8_t*>(arow + 32 * ks);
        arow += 256;

        f4_t acc[4];
#pragma unroll
        for (int p = 0; p < 4; ++p) { acc[p][0] = 0.f; acc[p][1] = 0.f; acc[p][2] = 0.f; acc[p][3] = 0.f; }
#pragma unroll
        for (int p = 0; p < 4; ++p)
#pragma unroll
            for (int ks = 0; ks < 8; ++ks)
                acc[p] = mfma16(a[ks], breg[p][ks], acc[p]);

#pragma unroll
        for (int p = 0; p < 4; ++p)
#pragma unroll
            for (int r = 0; r < 4; ++r)
                sh[w * 64 + 16 * p + l15][4 * lgp + r] = f2bf(acc[p][r] + bias[p]);
        __syncthreads();
        int q = threadIdx.x;
#pragma unroll
        for (int p = 0; p < 8; ++p) {
            int b2g = 8 * bh + p;
            size_t base = ((size_t)(d * 16 + b2g) * 1024 + t) * 2048 + ns * 256 + q;
            xg4[base]        = sh[q][2 * p];      // m=0
            xg4[base + 1024] = sh[q][2 * p + 1];  // m=1
        }
        __syncthreads();
    }
}

// ------- recurrence: 32 WGs = (dir, batch-pair); ALL weights in regs, 1 barrier/step ----
__global__ __launch_bounds__(512, 2) void lstm_kernel(const unsigned short* xg4,
        const signed char* qw, const float* sw, const float* h0, const float* c0,
        unsigned short* hs) {
    int bid = blockIdx.x;            // 0..31
    int b2 = bid & 15, d = bid >> 4;
    int tid = threadIdx.x;
    int w = tid >> 6, l = tid & 63, l15 = l & 15, lgp = l >> 4;

    __shared__ __attribute__((aligned(16))) signed char h8[2][2][320];
    __shared__ float red_sh[8];

    const signed char* qwd = qw + (size_t)d * 262144;

    i4_t wreg[4][2][4];
#pragma unroll
    for (int gt = 0; gt < 4; ++gt)
#pragma unroll
        for (int jt = 0; jt < 2; ++jt) {
            int n = 256 * gt + 32 * w + 16 * jt + l15;
#pragma unroll
            for (int ks = 0; ks < 4; ++ks)
                wreg[gt][jt][ks] = *reinterpret_cast<const i4_t*>(
                    qwd + (size_t)n * 256 + 64 * ks + 16 * lgp);
        }
#pragma unroll
    for (int gt = 0; gt < 4; ++gt)
#pragma unroll
        for (int jt = 0; jt < 2; ++jt)
#pragma unroll
            for (int ks = 0; ks < 4; ++ks)
                asm volatile("" : "+v"(wreg[gt][jt][ks]));   // keep resident

    int jt_c = lgp & 1, m_c = lgp >> 1;
    int j = 32 * w + 16 * jt_c + l15;

    float swv[4];
#pragma unroll
    for (int gt = 0; gt < 4; ++gt)
        swv[gt] = sw[d * 1024 + 256 * gt + j];
    float c = c0[((size_t)d * 32 + b2 * 2 + m_c) * 256 + j];

    int im = tid >> 8, ij = tid & 255;
    float v0 = h0[((size_t)d * 32 + b2 * 2 + im) * 256 + ij];
    float am = fabsf(v0);
#pragma unroll
    for (int off = 1; off < 64; off <<= 1)
        am = fmaxf(am, __shfl_xor(am, off));
    if (l == 0) red_sh[w] = am;
    __syncthreads();
    float bmax = red_sh[0];
#pragma unroll
    for (int q = 1; q < 8; ++q) bmax = fmaxf(bmax, red_sh[q]);
    bmax = fmaxf(bmax, 1e-20f);
    float s0 = bmax / 127.f;
    h8[1][im][ij] = (signed char)(int)__builtin_rintf(v0 * (127.f / bmax));

    float dq[4];
#pragma unroll
    for (int gt = 0; gt < 4; ++gt) dq[gt] = swv[gt] * s0;

    int t0 = d ? 1023 : 0;
    int xinc = d ? -2048 : 2048;
    int hinc = d ? -512 : 512;
    const unsigned short* xq = xg4 + ((size_t)(d * 16 + b2) * 1024 + t0) * 2048
                               + m_c * 1024 + j;
    unsigned short* hsp = hs + ((size_t)(b2 * 2 + m_c) * 1024 + t0) * 512 + d * 256 + j;

    unsigned short xc[4], xn[4];
#pragma unroll
    for (int gt = 0; gt < 4; ++gt) xc[gt] = xq[256 * gt];

    i4_t z4 = (i4_t){0, 0, 0, 0};
    asm volatile("" : "+v"(z4));

    __syncthreads();

    for (int s = 0; s < 1024; ++s) {
        int rp = (s + 1) & 1, wp = s & 1;

        if (s < 1023) {
            xq += xinc;
#pragma unroll
            for (int gt = 0; gt < 4; ++gt) xn[gt] = xq[256 * gt];
        }

        i4_t a[4];
#pragma unroll
        for (int ks = 0; ks < 4; ++ks)
            a[ks] = *reinterpret_cast<const i4_t*>(&h8[rp][l15 & 1][64 * ks + 16 * lgp]);

        i4_t acc[4][2];
#pragma unroll
        for (int gt = 0; gt < 4; ++gt)
#pragma unroll
            for (int jt = 0; jt < 2; ++jt) {
                acc[gt][jt] = __builtin_amdgcn_mfma_i32_16x16x64_i8(
                    a[0], wreg[gt][jt][0], z4, 0, 0, 0);
#pragma unroll
                for (int ks = 1; ks < 4; ++ks)
                    acc[gt][jt] = __builtin_amdgcn_mfma_i32_16x16x64_i8(
                        a[ks], wreg[gt][jt][ks], acc[gt][jt], 0, 0, 0);
            }

        int gi[4];
#pragma unroll
        for (int gt = 0; gt < 4; ++gt) {
            int e0 = jt_c ? acc[gt][1][0] : acc[gt][0][0];
            int e1 = jt_c ? acc[gt][1][1] : acc[gt][0][1];
            gi[gt] = m_c ? e1 : e0;
        }

        float pi = dq[0] * (float)gi[0] + bf2f(xc[0]);
        float pf = dq[1] * (float)gi[1] + bf2f(xc[1]);
        float pg = dq[2] * (float)gi[2] + bf2f(xc[2]);
        float po = dq[3] * (float)gi[3] + bf2f(xc[3]);
        float iv = sigf(pi), fv = sigf(pf), ov = sigf(po);
        float gv = tanh2_(pg);
        float cn = fv * c + iv * gv;
        c = cn;
        float hv = ov * tanh2_(cn);
        *hsp = f2bf(hv);
        hsp += hinc;
        h8[wp][m_c][j] = (signed char)(int)__builtin_rintf(hv * 127.f);

        if (s == 0) {
#pragma unroll
            for (int gt = 0; gt < 4; ++gt) dq[gt] = swv[gt] * (1.f / 127.f);
        }
#pragma unroll
        for (int gt = 0; gt < 4; ++gt) xc[gt] = xn[gt];

        asm volatile("s_waitcnt lgkmcnt(0)" ::: "memory");
        __builtin_amdgcn_sched_barrier(0);
        __builtin_amdgcn_s_barrier();
    }
}

// ---- fused logits+viterbi: 1 WG per sequence; logits -> LDS, then scan + backtrack ----
__global__ __launch_bounds__(256) void viterbi_kernel(const unsigned short* hs,
        const unsigned short* wout_bf, const float* b_out, const float* crf,
        float* out) {
    int b = blockIdx.x;
    int tid = threadIdx.x;
    int ww = tid >> 6, l = tid & 63, l15 = l & 15, lgp = l >> 4;

    __shared__ float lg[1024][16];          // 64 KiB logits
    __shared__ unsigned char bp[1024][16];  // 16 KiB backpointers
    __shared__ unsigned char pth[1024];

    // ---- phase 1: logits = hs[b] @ Wout^T + b_out, into LDS ----
    float bo = (l15 < NTAG) ? b_out[l15] : 0.0f;
    const unsigned short* brow = wout_bf + (size_t)l15 * 512 + 8 * lgp;
    for (int k = 0; k < 16; ++k) {
        int mt = ww + 4 * k;                // 0..63 t-tiles of 16
        const unsigned short* arow = hs + ((size_t)b * 1024 + mt * 16 + l15) * 512 + 8 * lgp;
        f4_t acc; acc[0] = 0.f; acc[1] = 0.f; acc[2] = 0.f; acc[3] = 0.f;
#pragma unroll
        for (int ks = 0; ks < 16; ++ks) {
            bf8_t a = *reinterpret_cast<const bf8_t*>(arow + 32 * ks);
            bf8_t bb = *reinterpret_cast<const bf8_t*>(brow + 32 * ks);
            acc = mfma16(a, bb, acc);
        }
#pragma unroll
        for (int r = 0; r < 4; ++r)
            lg[mt * 16 + 4 * lgp + r][l15] = acc[r] + bo;
    }
    __syncthreads();

    // ---- phase 2: scan (wave 0 only), max3-tree + equality-mask argmax ----
    if (ww == 0) {
        int j = l;
        float crfj[NTAG];
#pragma unroll
        for (int i = 0; i < NTAG; ++i)
            crfj[i] = (j < NTAG) ? crf[i * NTAG + j] : 0.0f;
        float v = (j < NTAG) ? lg[0][j] : -3.0e38f;
        for (int t = 1; t < 1024; ++t) {
            float sv[NTAG];
#pragma unroll
            for (int i = 0; i < NTAG; ++i)
                sv[i] = __shfl(v, i) + crfj[i];
            // value: max3-fused tree (depth ~3)
            float m0 = fmaxf(fmaxf(sv[0], sv[1]), sv[2]);
            float m1 = fmaxf(fmaxf(sv[3], sv[4]), sv[5]);
            float m2 = fmaxf(fmaxf(sv[6], sv[7]), sv[8]);
            float m3 = fmaxf(fmaxf(sv[9], sv[10]), sv[11]);
            float m4 = fmaxf(sv[12], sv[13]);
            float best = fmaxf(fmaxf(fmaxf(m0, m1), fmaxf(m2, m3)), m4);
            // arg: lowest index with sv[i]==best (== jnp.argmax tie rule)
            unsigned msk = 0;
#pragma unroll
            for (int i = 0; i < NTAG; ++i)
                msk |= (sv[i] == best) ? (1u << i) : 0u;
            int arg = __builtin_ctz(msk);
            float lt = (j < NTAG) ? lg[t][j] : 0.0f;
            v = (j < NTAG) ? (lt + best) : -3.0e38f;
            if (j < 16) bp[t][j] = (unsigned char)arg;
        }
        // final max over tags
        float best = -3.0e38f; int tag = 0;
#pragma unroll
        for (int jj = 0; jj < NTAG; ++jj) {
            float s = __shfl(v, jj);
            if (s > best) { best = s; tag = jj; }
        }
        if (j == 0) {
            out[b] = best;
            int tg = tag;
            pth[1023] = (unsigned char)tg;
            for (int t = 1023; t >= 1; --t) {
                tg = bp[t][tg];
                pth[t - 1] = (unsigned char)tg;
            }
        }
    }
    __syncthreads();
    float* pout = out + 32 + (size_t)b * 1024;
    for (int t = tid; t < 1024; t += 256)
        pout[t] = (float)pth[t];
}

extern "C" void kernel_launch(void* const* d_in, const int* in_sizes, int n_in,
                              void* d_out, int out_size, void* d_ws, size_t ws_size,
                              hipStream_t stream) {
    const int* sent = (const int*)d_in[0];
    const float* emb = (const float*)d_in[1];
    const float* wih_f = (const float*)d_in[2];
    const float* whh_f = (const float*)d_in[3];
    const float* bih_f = (const float*)d_in[4];
    const float* bhh_f = (const float*)d_in[5];
    const float* wih_b = (const float*)d_in[6];
    const float* whh_b = (const float*)d_in[7];
    const float* bih_b = (const float*)d_in[8];
    const float* bhh_b = (const float*)d_in[9];
    const float* h0 = (const float*)d_in[10];
    const float* c0 = (const float*)d_in[11];
    const float* wout = (const float*)d_in[12];
    const float* b_out = (const float*)d_in[13];
    const float* crf = (const float*)d_in[14];

    char* ws = (char*)d_ws;
    signed char* qw       = (signed char*)(ws + 0);               // 512 KiB
    float* sw             = (float*)(ws + 524288);                // 8 KiB
    unsigned short* wih_bf = (unsigned short*)(ws + 1048576);     // 1 MiB
    float* biasc          = (float*)(ws + 2097152);               // 8 KiB
    unsigned short* wout_bf = (unsigned short*)(ws + 2105344);    // 16 KiB
    unsigned short* xbf   = (unsigned short*)(ws + 2121728);      // 16 MiB
    unsigned short* xg4   = (unsigned short*)(ws + 18898944);     // 128 MiB
    unsigned short* hs    = (unsigned short*)(ws + 153116672);    // 32 MiB
    float* out = (float*)d_out;

    hipLaunchKernelGGL(setup_kernel, dim3(10792), dim3(256), 0, stream,
                       sent, emb, whh_f, whh_b, wih_f, wih_b,
                       bih_f, bhh_f, bih_b, bhh_b, wout,
                       xbf, qw, sw, wih_bf, biasc, wout_bf);
    hipLaunchKernelGGL(xproj_kernel, dim3(64, 16), dim3(256), 0, stream,
                       xbf, wih_bf, biasc, xg4);
    hipLaunchKernelGGL(lstm_kernel, dim3(32), dim3(512), 0, stream,
                       xg4, qw, sw, h0, c0, hs);
    hipLaunchKernelGGL(viterbi_kernel, dim3(32), dim3(256), 0, stream,
                       hs, wout_bf, b_out, crf, out);
}